// Round 13
// baseline (7565.434 us; speedup 1.0000x reference)
//
#include <hip/hip_runtime.h>
#include <hip/hip_bf16.h>
#include <stdint.h>

#define NSTEP 64
#define BATCH 32
#define EMBED_D 1536
#define ACT_D 16
#define DETER 2048
#define STOCH 512
#define HIDDEN 1024
#define FEAT 2560
#define NBLK 256

typedef __attribute__((ext_vector_type(8))) short bf16x8;
typedef __attribute__((ext_vector_type(4))) float f32x4;

#define MFMA16 __builtin_amdgcn_mfma_f32_16x16x32_bf16
#define AGENT __HIP_MEMORY_SCOPE_AGENT

__device__ __forceinline__ float eluf(float x) { return x > 0.f ? x : expf(x) - 1.f; }
__device__ __forceinline__ float sigf(float x) { return 1.f / (1.f + expf(-x)); }
__device__ __forceinline__ unsigned short f2bf(float f) {
    __hip_bfloat16 h = __float2bfloat16(f);
    return __builtin_bit_cast(unsigned short, h);
}
__device__ __forceinline__ float bf2f(unsigned short u) {
    unsigned v = ((unsigned)u) << 16;
    return __builtin_bit_cast(float, v);
}
__device__ __forceinline__ float blo(unsigned u) { return __builtin_bit_cast(float, u << 16); }
__device__ __forceinline__ float bhi(unsigned u) { return __builtin_bit_cast(float, u & 0xffff0000u); }

// ---- sc1 (agent-scope, fence-free) access helpers — r5/r12 proven data plane
__device__ __forceinline__ void stc_u32(unsigned* p, unsigned v) {
    __hip_atomic_store(p, v, __ATOMIC_RELAXED, AGENT);
}
__device__ __forceinline__ void stc_u64(unsigned long long* p, unsigned long long v) {
    __hip_atomic_store(p, v, __ATOMIC_RELAXED, AGENT);
}
__device__ __forceinline__ unsigned long long ldc_u64(const unsigned long long* p) {
    return __hip_atomic_load(p, __ATOMIC_RELAXED, AGENT);
}
__device__ __forceinline__ float ldc_f32(const float* p) {
    return __hip_atomic_load(p, __ATOMIC_RELAXED, AGENT);
}
__device__ __forceinline__ int ldc_i32(const int* p) {
    return __hip_atomic_load(p, __ATOMIC_RELAXED, AGENT);
}
__device__ __forceinline__ void stc_i32(int* p, int v) {
    __hip_atomic_store(p, v, __ATOMIC_RELAXED, AGENT);
}
__device__ __forceinline__ bf16x8 ldc_bf8(const unsigned short* p) {
    union { unsigned long long q[2]; bf16x8 v; } u;
    u.q[0] = ldc_u64((const unsigned long long*)p);
    u.q[1] = ldc_u64((const unsigned long long*)(p + 4));
    return u.v;
}
__device__ __forceinline__ ushort4 ldc_us4(const unsigned short* p) {
    unsigned long long q = ldc_u64((const unsigned long long*)p);
    return __builtin_bit_cast(ushort4, q);
}

// ---- flag-tree grid barrier, 32-way replicated release (r10/r12-verified)
__device__ __forceinline__ void gbar3(int* flags, int* release, int epoch) {
    asm volatile("s_waitcnt vmcnt(0)" ::: "memory");
    __syncthreads();
    if (blockIdx.x == 0) {
        int tid = threadIdx.x;
        if (tid >= 1 && tid < NBLK) {
            while (ldc_i32(&flags[tid * 32]) < epoch) __builtin_amdgcn_s_sleep(4);
        }
        asm volatile("" ::: "memory");
        __syncthreads();
        if (tid < 32) stc_i32(&release[tid * 32], epoch);
    } else {
        if (threadIdx.x == 0) {
            stc_i32(&flags[blockIdx.x * 32], epoch);
            int* rel = &release[(blockIdx.x & 31) * 32];
            while (ldc_i32(rel) < epoch) __builtin_amdgcn_s_sleep(4);
        }
        asm volatile("" ::: "memory");
        __syncthreads();
    }
}

// ---------------- all weight conversions in one kernel (bf16)
__global__ __launch_bounds__(256) void k_cvt_all(
    const float* __restrict__ s0, unsigned short* __restrict__ d0,
    const float* __restrict__ s1, unsigned short* __restrict__ d1,
    const float* __restrict__ s2, unsigned short* __restrict__ d2,
    const float* __restrict__ s3, unsigned short* __restrict__ d3,
    const float* __restrict__ s4, unsigned short* __restrict__ d4)
{
    long long e = ((long long)blockIdx.x * 256 + threadIdx.x) * 4;
    const float* src; unsigned short* dst; long long off;
    if (e < 524288)        { src = s0; dst = d0; off = e; }
    else if (e < 6815744)  { src = s1; dst = d1; off = e - 524288; }
    else if (e < 19398656) { src = s2; dst = d2; off = e - 6815744; }
    else if (e < 21495808) { src = s3; dst = d3; off = e - 19398656; }
    else if (e < 22544384) { src = s4; dst = d4; off = e - 21495808; }
    else return;
    float4 v = *reinterpret_cast<const float4*>(src + off);
    ushort4 o;
    o.x = f2bf(v.x); o.y = f2bf(v.y); o.z = f2bf(v.z); o.w = f2bf(v.w);
    *reinterpret_cast<ushort4*>(dst + off) = o;
}

// ---------------- setup: premasked h0 (f32+bf16), premasked z0 (bf16), flags=0
__global__ __launch_bounds__(256) void k_setup(
    const float* __restrict__ h0, const float* __restrict__ z0,
    const uint8_t* __restrict__ reset0,
    float* __restrict__ h0m, unsigned short* __restrict__ h16m0,
    unsigned short* __restrict__ z16m, int* __restrict__ flags)
{
    int gid = blockIdx.x * 256 + threadIdx.x;
    int idx = gid * 4;
    if (idx < BATCH * DETER) {
        int b = idx >> 11;
        float m = reset0[b] ? 0.f : 1.f;
        float4 v = *reinterpret_cast<const float4*>(h0 + idx);
        v.x *= m; v.y *= m; v.z *= m; v.w *= m;
        *reinterpret_cast<float4*>(h0m + idx) = v;
        ushort4 o;
        o.x = f2bf(v.x); o.y = f2bf(v.y); o.z = f2bf(v.z); o.w = f2bf(v.w);
        *reinterpret_cast<ushort4*>(h16m0 + idx) = o;
    } else if (idx < BATCH * DETER + BATCH * STOCH) {
        int zi = idx - BATCH * DETER;
        int b = zi >> 9;
        float m = reset0[b] ? 0.f : 1.f;
        float4 v = *reinterpret_cast<const float4*>(z0 + zi);
        ushort4 o;
        o.x = f2bf(v.x * m); o.y = f2bf(v.y * m); o.z = f2bf(v.z * m); o.w = f2bf(v.w * m);
        *reinterpret_cast<ushort4*>(z16m + zi) = o;
    }
    if (gid < 9216) flags[gid] = 0;
}

// ---------------- preA[r][j] = b_z[j] + action[r]@Wa[j]  (K=16)
__global__ __launch_bounds__(256) void k_preA(
    const float* __restrict__ action, const float* __restrict__ Wa,
    const float* __restrict__ bz, float* __restrict__ preA)
{
    __shared__ float al[16];
    int r = blockIdx.x, t = threadIdx.x;
    if (t < 16) al[t] = action[r * 16 + t];
    __syncthreads();
#pragma unroll
    for (int c = 0; c < 4; ++c) {
        int j = t + c * 256;
        const float* wr = Wa + j * 16;
        float s = bz[j];
#pragma unroll
        for (int k = 0; k < 16; ++k) s += al[k] * wr[k];
        preA[(size_t)r * 1024 + j] = s;
    }
}

// ---------------- one-shot MFMA GEMM (f32 sources, bf16 staging)
__global__ __launch_bounds__(256) void gemm_mfma(
    const float* __restrict__ A, int lda,
    const float* __restrict__ B, int ldb,
    const float* __restrict__ bias,
    float* __restrict__ C, int ldc, int K)
{
    __shared__ unsigned short Alds[64 * 72];
    __shared__ unsigned short Blds[64 * 72];
    int t = threadIdx.x;
    int nb = blockIdx.x, mb = blockIdx.y;
    int w = t >> 6, l = t & 63, l15 = l & 15, kg = l >> 4;
    f32x4 acc[4] = {{0,0,0,0},{0,0,0,0},{0,0,0,0},{0,0,0,0}};
    int srow = t >> 2, skq = (t & 3) * 16;
    const float* Asrc = A + (size_t)(mb * 64 + srow) * lda + skq;
    const float* Bsrc = B + (size_t)(nb * 64 + srow) * ldb + skq;
    unsigned short* Adst = &Alds[srow * 72 + skq];
    unsigned short* Bdst = &Blds[srow * 72 + skq];
    for (int kt = 0; kt < K; kt += 64) {
        __syncthreads();
#pragma unroll
        for (int c = 0; c < 16; c += 4) {
            float4 va = *reinterpret_cast<const float4*>(Asrc + kt + c);
            float4 vb = *reinterpret_cast<const float4*>(Bsrc + kt + c);
            ushort4 oa, ob;
            oa.x = f2bf(va.x); oa.y = f2bf(va.y); oa.z = f2bf(va.z); oa.w = f2bf(va.w);
            ob.x = f2bf(vb.x); ob.y = f2bf(vb.y); ob.z = f2bf(vb.z); ob.w = f2bf(vb.w);
            *reinterpret_cast<ushort4*>(Adst + c) = oa;
            *reinterpret_cast<ushort4*>(Bdst + c) = ob;
        }
        __syncthreads();
#pragma unroll
        for (int ks = 0; ks < 2; ks++) {
            bf16x8 a = *reinterpret_cast<const bf16x8*>(&Alds[(w * 16 + l15) * 72 + ks * 32 + kg * 8]);
#pragma unroll
            for (int nt = 0; nt < 4; nt++) {
                bf16x8 b = *reinterpret_cast<const bf16x8*>(&Blds[(nt * 16 + l15) * 72 + ks * 32 + kg * 8]);
                acc[nt] = MFMA16(a, b, acc[nt], 0, 0, 0);
            }
        }
    }
#pragma unroll
    for (int nt = 0; nt < 4; nt++) {
        int n = nb * 64 + nt * 16 + l15;
        float bv = bias[n];
#pragma unroll
        for (int i = 0; i < 4; i++) {
            C[(size_t)(mb * 64 + w * 16 + kg * 4 + i) * ldc + n] = acc[nt][i] + bv;
        }
    }
}

// ---------------- row LN+elu in place (f32)
__global__ __launch_bounds__(256) void ln_elu_rows(
    float* __restrict__ X, const float* __restrict__ g, const float* __restrict__ bb)
{
    __shared__ float sbuf[256], qbuf[256];
    int r = blockIdx.x, t = threadIdx.x;
    float* row = X + (size_t)r * HIDDEN;
    float4 v = reinterpret_cast<const float4*>(row)[t];
    sbuf[t] = (v.x + v.y) + (v.z + v.w);
    qbuf[t] = (v.x * v.x + v.y * v.y) + (v.z * v.z + v.w * v.w);
    __syncthreads();
    for (int off = 128; off > 0; off >>= 1) {
        if (t < off) { sbuf[t] += sbuf[t + off]; qbuf[t] += qbuf[t + off]; }
        __syncthreads();
    }
    float mean = sbuf[0] / HIDDEN;
    float var = qbuf[0] / HIDDEN - mean * mean;
    float rstd = rsqrtf(var + 1e-5f);
    float4 gg = reinterpret_cast<const float4*>(g)[t];
    float4 bv = reinterpret_cast<const float4*>(bb)[t];
    float4 o;
    o.x = eluf((v.x - mean) * rstd * gg.x + bv.x);
    o.y = eluf((v.y - mean) * rstd * gg.y + bv.y);
    o.z = eluf((v.z - mean) * rstd * gg.z + bv.z);
    o.w = eluf((v.w - mean) * rstd * gg.w + bv.w);
    reinterpret_cast<float4*>(row)[t] = o;
}

__global__ __launch_bounds__(256) void k_copy_last(
    const float* __restrict__ feat63, const float* __restrict__ samp63,
    float* __restrict__ hlast, float* __restrict__ zlast)
{
    int i = blockIdx.x * 256 + threadIdx.x;
    if (i < BATCH * DETER) {
        int b = i / DETER, k = i % DETER;
        hlast[i] = feat63[(size_t)b * FEAT + k];
    }
    if (i < BATCH * STOCH) zlast[i] = samp63[i];
}

// ======================= persistent scan: 256 blocks x 512 threads =======================
struct ScanArgs {
    const unsigned short *Wz16, *Wih16, *Whh16, *Wph16, *Wpo16;
    const float *bih, *bhh, *b_post;
    const float *ln_in_g, *ln_in_b, *ln_post_g, *ln_post_b;
    const float *h0m;
    const uint8_t *reset;
    const float *noises;
    float *postsPreA, *priorsPreE, *samples, *feats;
    unsigned short *z16m, *za16, *x2b, *h16u, *h16m0, *h16m1;
    float *x2parts;
    int *flags, *release;
};

__global__ __launch_bounds__(512, 1) void k_scan(ScanArgs a) {
    __shared__ char smem[140288];
    // carving per phase:
    //  P1: zl f32[512]@0 ; sbuf f32[512]@2048 ; qbuf f32[512]@4096
    //  P2: Asm 32x1032 bf16 @0 (66048B) ; cbuf f32[6144]@66048 (24576B) ; hbuf f32[512]@90624
    //  P3: Hs 32x2056 bf16 @0 (131584B) ; cb3 f32[2048]@131584 (8192B)
    //  P4: Asm @0 ; cb4 f32[2048]@66048 ; stat f32[64]@74240
    unsigned short* Asm = (unsigned short*)smem;
    float* cbuf = (float*)(smem + 66048);
    float* hbuf = (float*)(smem + 90624);

    const int bid = blockIdx.x;
    const int tid = threadIdx.x;
    const int w = tid >> 6, l = tid & 63, l15 = l & 15, kg = l >> 4;
    int epoch = 0;

    for (int t = 0; t < NSTEP; ++t) {
        const float* preA_t = a.postsPreA + (size_t)t * 32768;
        const float* preE_t = a.priorsPreE + (size_t)t * 32768;
        float* posts_t = a.postsPreA + (size_t)t * 32768;
        float* samples_t = a.samples + (size_t)t * 16384;
        float* feats_t = a.feats + (size_t)t * 81920;
        const float* featsPrev = a.feats + (size_t)(t - 1) * 81920;
        const unsigned short* h16cur = (t & 1) ? a.h16m1 : a.h16m0;   // premasked
        unsigned short* h16nxt = (t & 1) ? a.h16m0 : a.h16m1;

        // ========== P1: x1 = preA + z@Wz^T (premasked z), LN+elu -> za16 ==========
        // 32 blocks, 1 batch row each; f32 GEMV over 512 threads (2 cols each)
        if (bid < 32) {
            int b = bid;
            float* zl = (float*)smem;
            float* sbuf = (float*)(smem + 2048);
            float* qbuf = (float*)(smem + 4096);
            if (tid < 128) {
                unsigned long long v = ldc_u64((const unsigned long long*)(a.z16m + (size_t)b * 512) + tid);
                ushort4 u = __builtin_bit_cast(ushort4, v);
                float4 f;
                f.x = bf2f(u.x); f.y = bf2f(u.y); f.z = bf2f(u.z); f.w = bf2f(u.w);
                *reinterpret_cast<float4*>(zl + tid * 4) = f;
            }
            __syncthreads();
            int j0 = tid * 2;
            const unsigned short* wr0 = a.Wz16 + (size_t)j0 * 512;
            const unsigned short* wr1 = wr0 + 512;
            float acc0 = 0.f, acc1 = 0.f;
#pragma unroll 4
            for (int k = 0; k < 512; k += 8) {
                float4 zA = *reinterpret_cast<const float4*>(zl + k);
                float4 zB = *reinterpret_cast<const float4*>(zl + k + 4);
                uint4 q0 = *reinterpret_cast<const uint4*>(wr0 + k);
                uint4 q1 = *reinterpret_cast<const uint4*>(wr1 + k);
                acc0 += blo(q0.x) * zA.x + bhi(q0.x) * zA.y + blo(q0.y) * zA.z + bhi(q0.y) * zA.w
                      + blo(q0.z) * zB.x + bhi(q0.z) * zB.y + blo(q0.w) * zB.z + bhi(q0.w) * zB.w;
                acc1 += blo(q1.x) * zA.x + bhi(q1.x) * zA.y + blo(q1.y) * zA.z + bhi(q1.y) * zA.w
                      + blo(q1.z) * zB.x + bhi(q1.z) * zB.y + blo(q1.w) * zB.z + bhi(q1.w) * zB.w;
            }
            float x0 = acc0 + preA_t[(size_t)b * 1024 + j0];
            float x1v = acc1 + preA_t[(size_t)b * 1024 + j0 + 1];
            sbuf[tid] = x0 + x1v;
            qbuf[tid] = x0 * x0 + x1v * x1v;
            __syncthreads();
            for (int off = 256; off > 0; off >>= 1) {
                if (tid < off) { sbuf[tid] += sbuf[tid + off]; qbuf[tid] += qbuf[tid + off]; }
                __syncthreads();
            }
            float mean = sbuf[0] * (1.f / 1024.f);
            float var = qbuf[0] * (1.f / 1024.f) - mean * mean;
            float rstd = rsqrtf(var + 1e-5f);
            float y0 = eluf((x0 - mean) * rstd * a.ln_in_g[j0] + a.ln_in_b[j0]);
            float y1 = eluf((x1v - mean) * rstd * a.ln_in_g[j0 + 1] + a.ln_in_b[j0 + 1]);
            stc_u32((unsigned*)(a.za16 + (size_t)b * 1024 + j0),
                    (unsigned)f2bf(y0) | ((unsigned)f2bf(y1) << 16));
        }
        epoch++; gbar3(a.flags, a.release, epoch);

        // ========== P2: gates MFMA (K-split, 8 waves) + GRU combine (128 blocks) ==========
        if (bid < 128) {
            int j0 = bid * 16;
            // stage za16 -> Asm: 32 rows x 256 u64 = 8192 u64 (FIXED count)
#pragma unroll
            for (int i = 0; i < 16; ++i) {
                int idx = tid + i * 512;
                int r = idx >> 8, c = idx & 255;
                unsigned long long v = ldc_u64((const unsigned long long*)a.za16 + idx);
                *reinterpret_cast<unsigned long long*>(Asm + r * 1032 + c * 4) = v;
            }
            __syncthreads();
            f32x4 cr = {0,0,0,0}, cu = {0,0,0,0}, cn = {0,0,0,0};
            if (w < 4) {
                // gi: rowgrp = w&1, K-half = w>>1 (512 each)
                int rowgrp = w & 1, kh = w >> 1;
                const unsigned short* ap = Asm + (rowgrp * 16 + l15) * 1032 + kh * 512 + kg * 8;
                const unsigned short* br = a.Wih16 + (size_t)(j0 + l15) * 1024 + kh * 512 + kg * 8;
                const unsigned short* bu = br + (size_t)2048 * 1024;
                const unsigned short* bn = bu + (size_t)2048 * 1024;
#pragma unroll 4
                for (int ks = 0; ks < 16; ++ks) {
                    bf16x8 av = *reinterpret_cast<const bf16x8*>(ap + ks * 32);
                    cr = MFMA16(av, *reinterpret_cast<const bf16x8*>(br + ks * 32), cr, 0, 0, 0);
                    cu = MFMA16(av, *reinterpret_cast<const bf16x8*>(bu + ks * 32), cu, 0, 0, 0);
                    cn = MFMA16(av, *reinterpret_cast<const bf16x8*>(bn + ks * 32), cn, 0, 0, 0);
                }
            } else {
                // gh: rowgrp = (w-4)&1, K-half = (w-4)>>1 (1024 each); h16cur premasked
                int idx = w - 4, rowgrp = idx & 1, kh = idx >> 1;
                const unsigned short* hp = h16cur + (size_t)(rowgrp * 16 + l15) * 2048 + kh * 1024 + kg * 8;
                const unsigned short* br = a.Whh16 + (size_t)(j0 + l15) * 2048 + kh * 1024 + kg * 8;
                const unsigned short* bu = br + (size_t)2048 * 2048;
                const unsigned short* bn = bu + (size_t)2048 * 2048;
#pragma unroll 4
                for (int ks = 0; ks < 32; ++ks) {
                    bf16x8 av = ldc_bf8(hp + ks * 32);
                    cr = MFMA16(av, *reinterpret_cast<const bf16x8*>(br + ks * 32), cr, 0, 0, 0);
                    cu = MFMA16(av, *reinterpret_cast<const bf16x8*>(bu + ks * 32), cu, 0, 0, 0);
                    cn = MFMA16(av, *reinterpret_cast<const bf16x8*>(bn + ks * 32), cn, 0, 0, 0);
                }
            }
#pragma unroll
            for (int i = 0; i < 4; ++i) {
                int o = (kg * 4 + i) * 16 + l15;
                cbuf[w * 768 + 0 * 256 + o] = cr[i];
                cbuf[w * 768 + 1 * 256 + o] = cu[i];
                cbuf[w * 768 + 2 * 256 + o] = cn[i];
            }
            __syncthreads();
            // combine: 512 threads, one (row,col) each
            {
                int row = tid >> 4, col = tid & 15;
                int rowgrp = row >> 4, rr = row & 15;
                int o = rr * 16 + col;
                int j = j0 + col;
                float gr = cbuf[rowgrp * 768 + 0 * 256 + o] + cbuf[(2 + rowgrp) * 768 + 0 * 256 + o] + a.bih[j];
                float gu = cbuf[rowgrp * 768 + 1 * 256 + o] + cbuf[(2 + rowgrp) * 768 + 1 * 256 + o] + a.bih[j + 2048];
                float gn = cbuf[rowgrp * 768 + 2 * 256 + o] + cbuf[(2 + rowgrp) * 768 + 2 * 256 + o] + a.bih[j + 4096];
                float hr = cbuf[(4 + rowgrp) * 768 + 0 * 256 + o] + cbuf[(6 + rowgrp) * 768 + 0 * 256 + o] + a.bhh[j];
                float hu = cbuf[(4 + rowgrp) * 768 + 1 * 256 + o] + cbuf[(6 + rowgrp) * 768 + 1 * 256 + o] + a.bhh[j + 2048];
                float hn = cbuf[(4 + rowgrp) * 768 + 2 * 256 + o] + cbuf[(6 + rowgrp) * 768 + 2 * 256 + o] + a.bhh[j + 4096];
                float r_ = sigf(gr + hr), u_ = sigf(gu + hu);
                float cand = tanhf(gn + r_ * hn);
                float m = a.reset[t * 32 + row] ? 0.f : 1.f;
                float hpv = (t == 0) ? a.h0m[(size_t)row * 2048 + j]
                                     : ldc_f32(featsPrev + (size_t)row * 2560 + j);
                hbuf[row * 16 + col] = (1.f - u_) * cand + u_ * (m * hpv);
            }
            __syncthreads();
            if (tid < 256) {
                int b = tid >> 3, c2 = (tid & 7) * 2;
                float h0v = hbuf[b * 16 + c2], h1v = hbuf[b * 16 + c2 + 1];
                int j = j0 + c2;
                union { float f[2]; unsigned long long u; } fu;
                fu.f[0] = h0v; fu.f[1] = h1v;
                stc_u64((unsigned long long*)(feats_t + (size_t)b * 2560 + j), fu.u);
                unsigned short g0 = f2bf(h0v), g1 = f2bf(h1v);
                stc_u32((unsigned*)(a.h16u + (size_t)b * 2048 + j),
                        (unsigned)g0 | ((unsigned)g1 << 16));
                float mn = (t < 63) ? (a.reset[(t + 1) * 32 + b] ? 0.f : 1.f) : 1.f;
                unsigned short n0 = f2bf(h0v * mn), n1 = f2bf(h1v * mn);
                stc_u32((unsigned*)(h16nxt + (size_t)b * 2048 + j),
                        (unsigned)n0 | ((unsigned)n1 << 16));
            }
        }
        epoch++; gbar3(a.flags, a.release, epoch);

        // ========== P3: x2 = preE + h @ Wph^T (K-split, 8 waves; 64 blocks) ==========
        if (bid < 64) {
            int j0 = bid * 16;
            unsigned short* Hs = (unsigned short*)smem;
            float* cb3 = (float*)(smem + 131584);
            // stage h16u -> Hs: 32 rows x 512 u64 = 16384 u64 (FIXED count)
#pragma unroll
            for (int i = 0; i < 32; ++i) {
                int idx = tid + i * 512;
                int r = idx >> 9, c = idx & 511;
                unsigned long long v = ldc_u64((const unsigned long long*)a.h16u + idx);
                *reinterpret_cast<unsigned long long*>(Hs + r * 2056 + c * 4) = v;
            }
            __syncthreads();
            int rowgrp = w & 1, kq = w >> 1;     // 4 K-quarters of 512
            const unsigned short* ap = Hs + (rowgrp * 16 + l15) * 2056 + kq * 512 + kg * 8;
            const unsigned short* Bp = a.Wph16 + (size_t)(j0 + l15) * 2048 + kq * 512 + kg * 8;
            f32x4 c0 = {0,0,0,0};
#pragma unroll 4
            for (int ks = 0; ks < 16; ++ks) {
                c0 = MFMA16(*reinterpret_cast<const bf16x8*>(ap + ks * 32),
                            *reinterpret_cast<const bf16x8*>(Bp + ks * 32), c0, 0, 0, 0);
            }
#pragma unroll
            for (int i = 0; i < 4; ++i)
                cb3[w * 256 + (kg * 4 + i) * 16 + l15] = c0[i];
            __syncthreads();
            if (tid < 256) {
                int r = tid >> 3, c2 = (tid & 7) * 2;
                int rowgrp2 = r >> 4, rr = r & 15;
                float v0 = 0.f, v1 = 0.f;
#pragma unroll
                for (int kq2 = 0; kq2 < 4; ++kq2) {
                    v0 += cb3[(kq2 * 2 + rowgrp2) * 256 + rr * 16 + c2];
                    v1 += cb3[(kq2 * 2 + rowgrp2) * 256 + rr * 16 + c2 + 1];
                }
                v0 += preE_t[(size_t)r * 1024 + j0 + c2];
                v1 += preE_t[(size_t)r * 1024 + j0 + c2 + 1];
                unsigned short u0 = f2bf(v0), u1 = f2bf(v1);
                stc_u32((unsigned*)(a.x2b + (size_t)r * 1024 + j0 + c2),
                        (unsigned)u0 | ((unsigned)u1 << 16));
                float w0 = bf2f(u0), w1 = bf2f(u1);
                float s = w0 + w1, q = w0 * w0 + w1 * w1;
                s += __shfl_xor(s, 1); q += __shfl_xor(q, 1);
                s += __shfl_xor(s, 2); q += __shfl_xor(q, 2);
                s += __shfl_xor(s, 4); q += __shfl_xor(q, 4);
                if ((tid & 7) == 0) {
                    union { float f[2]; unsigned long long u; } pu;
                    pu.f[0] = s; pu.f[1] = q;
                    stc_u64((unsigned long long*)(a.x2parts + ((size_t)bid * 32 + r) * 2), pu.u);
                }
            }
        }
        epoch++; gbar3(a.flags, a.release, epoch);

        // ========== P4: post MFMA + sample (K-split, 8 waves; 32 blocks) ==========
        if (bid < 32) {
            int j0 = bid * 16;
            float* cb4 = (float*)(smem + 66048);
            float* stat = (float*)(smem + 74240);
            if (tid < 32) {
                float s = 0.f, q = 0.f;
                for (int i = 0; i < 64; ++i) {
                    union { unsigned long long u; float f[2]; } c;
                    c.u = ldc_u64((const unsigned long long*)(a.x2parts + (size_t)(i * 32 + tid) * 2));
                    s += c.f[0]; q += c.f[1];
                }
                float mean = s * (1.f / 1024.f);
                float var = q * (1.f / 1024.f) - mean * mean;
                stat[tid] = mean;
                stat[32 + tid] = rsqrtf(var + 1e-5f);
            }
            __syncthreads();
            // LN+elu fill: 512 threads, row = tid&31, col-group = (tid>>5)*64
            {
                int row = tid & 31, kb = (tid >> 5) * 64;
                float mean = stat[row], rstd = stat[32 + row];
#pragma unroll 2
                for (int c = 0; c < 8; ++c) {
                    int k = kb + c * 8;
                    ushort4 u0 = ldc_us4(a.x2b + (size_t)row * 1024 + k);
                    ushort4 u1 = ldc_us4(a.x2b + (size_t)row * 1024 + k + 4);
                    float4 g0 = *reinterpret_cast<const float4*>(a.ln_post_g + k);
                    float4 g1 = *reinterpret_cast<const float4*>(a.ln_post_g + k + 4);
                    float4 b0 = *reinterpret_cast<const float4*>(a.ln_post_b + k);
                    float4 b1 = *reinterpret_cast<const float4*>(a.ln_post_b + k + 4);
                    ushort4 o0, o1;
                    o0.x = f2bf(eluf((bf2f(u0.x) - mean) * rstd * g0.x + b0.x));
                    o0.y = f2bf(eluf((bf2f(u0.y) - mean) * rstd * g0.y + b0.y));
                    o0.z = f2bf(eluf((bf2f(u0.z) - mean) * rstd * g0.z + b0.z));
                    o0.w = f2bf(eluf((bf2f(u0.w) - mean) * rstd * g0.w + b0.w));
                    o1.x = f2bf(eluf((bf2f(u1.x) - mean) * rstd * g1.x + b1.x));
                    o1.y = f2bf(eluf((bf2f(u1.y) - mean) * rstd * g1.y + b1.y));
                    o1.z = f2bf(eluf((bf2f(u1.z) - mean) * rstd * g1.z + b1.z));
                    o1.w = f2bf(eluf((bf2f(u1.w) - mean) * rstd * g1.w + b1.w));
                    *reinterpret_cast<ushort4*>(Asm + row * 1032 + k) = o0;
                    *reinterpret_cast<ushort4*>(Asm + row * 1032 + k + 4) = o1;
                }
            }
            __syncthreads();
            int tile = w >> 2, mt = (w >> 1) & 1, kh = w & 1;
            const unsigned short* ap = Asm + (mt * 16 + l15) * 1032 + kh * 512 + kg * 8;
            int n = tile ? (512 + j0 + l15) : (j0 + l15);
            const unsigned short* Bp = a.Wpo16 + (size_t)n * 1024 + kh * 512 + kg * 8;
            f32x4 c = {0,0,0,0};
#pragma unroll 4
            for (int ks = 0; ks < 16; ++ks) {
                c = MFMA16(*reinterpret_cast<const bf16x8*>(ap + ks * 32),
                           *reinterpret_cast<const bf16x8*>(Bp + ks * 32), c, 0, 0, 0);
            }
#pragma unroll
            for (int i = 0; i < 4; ++i)
                cb4[w * 256 + (kg * 4 + i) * 16 + l15] = c[i];
            __syncthreads();
            if (tid < 256) {
                int b = tid >> 3, c2 = (tid & 7) * 2;
                int j = j0 + c2;
                int mt2 = b >> 4, rr = b & 15, o = rr * 16;
                float pm0 = cb4[(mt2 * 2 + 0) * 256 + o + c2] + cb4[(mt2 * 2 + 1) * 256 + o + c2] + a.b_post[j];
                float pm1 = cb4[(mt2 * 2 + 0) * 256 + o + c2 + 1] + cb4[(mt2 * 2 + 1) * 256 + o + c2 + 1] + a.b_post[j + 1];
                float ps0 = cb4[(4 + mt2 * 2 + 0) * 256 + o + c2] + cb4[(4 + mt2 * 2 + 1) * 256 + o + c2] + a.b_post[512 + j];
                float ps1 = cb4[(4 + mt2 * 2 + 0) * 256 + o + c2 + 1] + cb4[(4 + mt2 * 2 + 1) * 256 + o + c2 + 1] + a.b_post[512 + j + 1];
                posts_t[(size_t)b * 1024 + j] = pm0;
                posts_t[(size_t)b * 1024 + j + 1] = pm1;
                posts_t[(size_t)b * 1024 + 512 + j] = ps0;
                posts_t[(size_t)b * 1024 + 512 + j + 1] = ps1;
                float sp0 = fmaxf(ps0, 0.f) + log1pf(expf(-fabsf(ps0)));
                float sp1 = fmaxf(ps1, 0.f) + log1pf(expf(-fabsf(ps1)));
                float n0v = a.noises[(size_t)t * 16384 + b * 512 + j];
                float n1v = a.noises[(size_t)t * 16384 + b * 512 + j + 1];
                float smp0 = pm0 + (sp0 + 0.1f) * n0v;
                float smp1 = pm1 + (sp1 + 0.1f) * n1v;
                samples_t[(size_t)b * 512 + j] = smp0;
                samples_t[(size_t)b * 512 + j + 1] = smp1;
                feats_t[(size_t)b * 2560 + 2048 + j] = smp0;
                feats_t[(size_t)b * 2560 + 2048 + j + 1] = smp1;
                float mn = (t < 63) ? (a.reset[(t + 1) * 32 + b] ? 0.f : 1.f) : 1.f;
                unsigned short z0_ = f2bf(smp0 * mn), z1_ = f2bf(smp1 * mn);
                stc_u32((unsigned*)(a.z16m + (size_t)b * 512 + j),
                        (unsigned)z0_ | ((unsigned)z1_ << 16));
            }
        }
        epoch++; gbar3(a.flags, a.release, epoch);
    }
}

// ws byte offsets (r12 layout; x1b reused as za16)
#define WS_WZ16   ((size_t)0)
#define WS_WIH16  ((size_t)1048576)
#define WS_WHH16  ((size_t)13631488)
#define WS_WPH16  ((size_t)38797312)
#define WS_WPO16  ((size_t)42991616)
#define WS_Z16M   ((size_t)45088768)
#define WS_H16M0  ((size_t)45121536)
#define WS_H16M1  ((size_t)45252608)
#define WS_H16U   ((size_t)45383680)
#define WS_H0M    ((size_t)45514752)
#define WS_ZA16   ((size_t)45776896)
#define WS_X2B    ((size_t)45842432)
#define WS_X1P    ((size_t)45907968)
#define WS_X2P    ((size_t)45924352)
#define WS_FLAGS  ((size_t)45940736)
#define WS_REL    ((size_t)45973504)
#define WS_PRX    WS_WIH16

extern "C" void kernel_launch(void* const* d_in, const int* in_sizes, int n_in,
                              void* d_out, int out_size, void* d_ws, size_t ws_size,
                              hipStream_t stream)
{
    (void)in_sizes; (void)n_in; (void)out_size; (void)ws_size;
    const float*   embed  = (const float*)d_in[0];
    const float*   action = (const float*)d_in[1];
    const uint8_t* reset  = (const uint8_t*)d_in[2];
    const float*   h0     = (const float*)d_in[3];
    const float*   z0     = (const float*)d_in[4];
    const float*   noises = (const float*)d_in[5];
    const float*   W_z    = (const float*)d_in[6];
    const float*   b_z    = (const float*)d_in[7];
    const float*   W_a    = (const float*)d_in[8];
    const float*   ln_in_g = (const float*)d_in[9];
    const float*   ln_in_b = (const float*)d_in[10];
    const float*   Wih    = (const float*)d_in[11];
    const float*   Whh    = (const float*)d_in[12];
    const float*   bih    = (const float*)d_in[13];
    const float*   bhh    = (const float*)d_in[14];
    const float*   W_ph   = (const float*)d_in[15];
    const float*   b_ph   = (const float*)d_in[16];
    const float*   W_pe   = (const float*)d_in[17];
    const float*   ln_post_g = (const float*)d_in[18];
    const float*   ln_post_b = (const float*)d_in[19];
    const float*   W_post = (const float*)d_in[20];
    const float*   b_post = (const float*)d_in[21];
    const float*   W_prh  = (const float*)d_in[22];
    const float*   b_prh  = (const float*)d_in[23];
    const float*   ln_pr_g = (const float*)d_in[24];
    const float*   ln_pr_b = (const float*)d_in[25];
    const float*   W_pr   = (const float*)d_in[26];
    const float*   b_pr   = (const float*)d_in[27];

    float* out     = (float*)d_out;
    float* priors  = out;                  // preE lives here during scan
    float* posts   = out + 2097152;        // preA lives here during scan
    float* samples = out + 4194304;
    float* feats   = out + 5242880;
    float* hlast   = out + 10485760;
    float* zlast   = out + 10551296;

    char* ws = (char*)d_ws;
    unsigned short* Wz16  = (unsigned short*)(ws + WS_WZ16);
    unsigned short* Wih16 = (unsigned short*)(ws + WS_WIH16);
    unsigned short* Whh16 = (unsigned short*)(ws + WS_WHH16);
    unsigned short* Wph16 = (unsigned short*)(ws + WS_WPH16);
    unsigned short* Wpo16 = (unsigned short*)(ws + WS_WPO16);
    unsigned short* z16m  = (unsigned short*)(ws + WS_Z16M);
    unsigned short* h16m0 = (unsigned short*)(ws + WS_H16M0);
    unsigned short* h16m1 = (unsigned short*)(ws + WS_H16M1);
    unsigned short* h16u  = (unsigned short*)(ws + WS_H16U);
    float*          h0m   = (float*)(ws + WS_H0M);
    unsigned short* za16  = (unsigned short*)(ws + WS_ZA16);
    unsigned short* x2b   = (unsigned short*)(ws + WS_X2B);
    float*          x2p   = (float*)(ws + WS_X2P);
    int*            flags = (int*)(ws + WS_FLAGS);
    int*            release = (int*)(ws + WS_REL);
    float*          prx   = (float*)(ws + WS_PRX);

    dim3 blk(256);

    k_cvt_all<<<dim3(22016), blk, 0, stream>>>(W_z, Wz16, Wih, Wih16, Whh, Whh16,
                                               W_ph, Wph16, W_post, Wpo16);
    k_setup<<<dim3(80), blk, 0, stream>>>(h0, z0, reset, h0m, h16m0, z16m, flags);

    // preA -> posts region ; preE -> priors region
    k_preA<<<dim3(2048), blk, 0, stream>>>(action, W_a, b_z, posts);
    gemm_mfma<<<dim3(16, 32), blk, 0, stream>>>(embed, EMBED_D, W_pe, EMBED_D, b_ph,
                                                priors, HIDDEN, EMBED_D);

    ScanArgs sa;
    sa.Wz16 = Wz16; sa.Wih16 = Wih16; sa.Whh16 = Whh16; sa.Wph16 = Wph16; sa.Wpo16 = Wpo16;
    sa.bih = bih; sa.bhh = bhh; sa.b_post = b_post;
    sa.ln_in_g = ln_in_g; sa.ln_in_b = ln_in_b; sa.ln_post_g = ln_post_g; sa.ln_post_b = ln_post_b;
    sa.h0m = h0m; sa.reset = reset; sa.noises = noises;
    sa.postsPreA = posts; sa.priorsPreE = priors; sa.samples = samples; sa.feats = feats;
    sa.z16m = z16m; sa.za16 = za16; sa.x2b = x2b; sa.h16u = h16u;
    sa.h16m0 = h16m0; sa.h16m1 = h16m1;
    sa.x2parts = x2p;
    sa.flags = flags; sa.release = release;

    // Plain launch: 256 blocks x 512 threads; LDS 140288 B -> 1 block/CU, all co-resident.
    k_scan<<<dim3(NBLK), dim3(512), 0, stream>>>(sa);

    // prior chain
    gemm_mfma<<<dim3(16, 32), blk, 0, stream>>>(feats, FEAT, W_prh, DETER, b_prh,
                                                prx, HIDDEN, DETER);
    ln_elu_rows<<<dim3(2048), blk, 0, stream>>>(prx, ln_pr_g, ln_pr_b);
    gemm_mfma<<<dim3(16, 32), blk, 0, stream>>>(prx, HIDDEN, W_pr, HIDDEN, b_pr,
                                                priors, HIDDEN, HIDDEN);

    k_copy_last<<<dim3(256), blk, 0, stream>>>(
        feats + (size_t)(NSTEP - 1) * BATCH * FEAT,
        samples + (size_t)(NSTEP - 1) * BATCH * STOCH,
        hlast, zlast);
}

// Round 14
// 4510.264 us; speedup vs baseline: 1.6774x; 1.6774x over previous
//
#include <hip/hip_runtime.h>
#include <hip/hip_bf16.h>
#include <stdint.h>

#define NSTEP 64
#define BATCH 32
#define EMBED_D 1536
#define ACT_D 16
#define DETER 2048
#define STOCH 512
#define HIDDEN 1024
#define FEAT 2560
#define NBLK 256

typedef __attribute__((ext_vector_type(8))) short bf16x8;
typedef __attribute__((ext_vector_type(4))) float f32x4;

#define MFMA16 __builtin_amdgcn_mfma_f32_16x16x32_bf16
#define AGENT __HIP_MEMORY_SCOPE_AGENT

__device__ __forceinline__ float eluf(float x) { return x > 0.f ? x : expf(x) - 1.f; }
__device__ __forceinline__ float sigf(float x) { return 1.f / (1.f + expf(-x)); }
__device__ __forceinline__ unsigned short f2bf(float f) {
    __hip_bfloat16 h = __float2bfloat16(f);
    return __builtin_bit_cast(unsigned short, h);
}
__device__ __forceinline__ float bf2f(unsigned short u) {
    unsigned v = ((unsigned)u) << 16;
    return __builtin_bit_cast(float, v);
}

// ---- sc1 (agent-scope, fence-free) access helpers — r5/r12 proven data plane
__device__ __forceinline__ void stc_u32(unsigned* p, unsigned v) {
    __hip_atomic_store(p, v, __ATOMIC_RELAXED, AGENT);
}
__device__ __forceinline__ void stc_u64(unsigned long long* p, unsigned long long v) {
    __hip_atomic_store(p, v, __ATOMIC_RELAXED, AGENT);
}
__device__ __forceinline__ unsigned long long ldc_u64(const unsigned long long* p) {
    return __hip_atomic_load(p, __ATOMIC_RELAXED, AGENT);
}
__device__ __forceinline__ float ldc_f32(const float* p) {
    return __hip_atomic_load(p, __ATOMIC_RELAXED, AGENT);
}
__device__ __forceinline__ int ldc_i32(const int* p) {
    return __hip_atomic_load(p, __ATOMIC_RELAXED, AGENT);
}
__device__ __forceinline__ void stc_i32(int* p, int v) {
    __hip_atomic_store(p, v, __ATOMIC_RELAXED, AGENT);
}
__device__ __forceinline__ bf16x8 ldc_bf8(const unsigned short* p) {
    union { unsigned long long q[2]; bf16x8 v; } u;
    u.q[0] = ldc_u64((const unsigned long long*)p);
    u.q[1] = ldc_u64((const unsigned long long*)(p + 4));
    return u.v;
}
__device__ __forceinline__ ushort4 ldc_us4(const unsigned short* p) {
    unsigned long long q = ldc_u64((const unsigned long long*)p);
    return __builtin_bit_cast(ushort4, q);
}

// ---- flag-tree grid barrier, 32-way replicated release (r10/r12-verified)
__device__ __forceinline__ void gbar3(int* flags, int* release, int epoch) {
    asm volatile("s_waitcnt vmcnt(0)" ::: "memory");
    __syncthreads();
    if (blockIdx.x == 0) {
        int tid = threadIdx.x;
        if (tid >= 1 && tid < NBLK) {
            while (ldc_i32(&flags[tid * 32]) < epoch) __builtin_amdgcn_s_sleep(4);
        }
        asm volatile("" ::: "memory");
        __syncthreads();
        if (tid < 32) stc_i32(&release[tid * 32], epoch);
    } else {
        if (threadIdx.x == 0) {
            stc_i32(&flags[blockIdx.x * 32], epoch);
            int* rel = &release[(blockIdx.x & 31) * 32];
            while (ldc_i32(rel) < epoch) __builtin_amdgcn_s_sleep(4);
        }
        asm volatile("" ::: "memory");
        __syncthreads();
    }
}

// ---------------- all weight conversions in one kernel (bf16)
__global__ __launch_bounds__(256) void k_cvt_all(
    const float* __restrict__ s0, unsigned short* __restrict__ d0,
    const float* __restrict__ s1, unsigned short* __restrict__ d1,
    const float* __restrict__ s2, unsigned short* __restrict__ d2,
    const float* __restrict__ s3, unsigned short* __restrict__ d3,
    const float* __restrict__ s4, unsigned short* __restrict__ d4)
{
    long long e = ((long long)blockIdx.x * 256 + threadIdx.x) * 4;
    const float* src; unsigned short* dst; long long off;
    if (e < 524288)        { src = s0; dst = d0; off = e; }
    else if (e < 6815744)  { src = s1; dst = d1; off = e - 524288; }
    else if (e < 19398656) { src = s2; dst = d2; off = e - 6815744; }
    else if (e < 21495808) { src = s3; dst = d3; off = e - 19398656; }
    else if (e < 22544384) { src = s4; dst = d4; off = e - 21495808; }
    else return;
    float4 v = *reinterpret_cast<const float4*>(src + off);
    ushort4 o;
    o.x = f2bf(v.x); o.y = f2bf(v.y); o.z = f2bf(v.z); o.w = f2bf(v.w);
    *reinterpret_cast<ushort4*>(dst + off) = o;
}

// ---------------- setup: premasked h0 (f32+bf16), premasked z0 (bf16), flags=0
__global__ __launch_bounds__(256) void k_setup(
    const float* __restrict__ h0, const float* __restrict__ z0,
    const uint8_t* __restrict__ reset0,
    float* __restrict__ h0m, unsigned short* __restrict__ h16m0,
    unsigned short* __restrict__ z16m, int* __restrict__ flags)
{
    int gid = blockIdx.x * 256 + threadIdx.x;
    int idx = gid * 4;
    if (idx < BATCH * DETER) {
        int b = idx >> 11;
        float m = reset0[b] ? 0.f : 1.f;
        float4 v = *reinterpret_cast<const float4*>(h0 + idx);
        v.x *= m; v.y *= m; v.z *= m; v.w *= m;
        *reinterpret_cast<float4*>(h0m + idx) = v;
        ushort4 o;
        o.x = f2bf(v.x); o.y = f2bf(v.y); o.z = f2bf(v.z); o.w = f2bf(v.w);
        *reinterpret_cast<ushort4*>(h16m0 + idx) = o;
    } else if (idx < BATCH * DETER + BATCH * STOCH) {
        int zi = idx - BATCH * DETER;
        int b = zi >> 9;
        float m = reset0[b] ? 0.f : 1.f;
        float4 v = *reinterpret_cast<const float4*>(z0 + zi);
        ushort4 o;
        o.x = f2bf(v.x * m); o.y = f2bf(v.y * m); o.z = f2bf(v.z * m); o.w = f2bf(v.w * m);
        *reinterpret_cast<ushort4*>(z16m + zi) = o;
    }
    if (gid < 9216) flags[gid] = 0;
}

// ---------------- preA[r][j] = b_z[j] + action[r]@Wa[j]  (K=16)
__global__ __launch_bounds__(256) void k_preA(
    const float* __restrict__ action, const float* __restrict__ Wa,
    const float* __restrict__ bz, float* __restrict__ preA)
{
    __shared__ float al[16];
    int r = blockIdx.x, t = threadIdx.x;
    if (t < 16) al[t] = action[r * 16 + t];
    __syncthreads();
#pragma unroll
    for (int c = 0; c < 4; ++c) {
        int j = t + c * 256;
        const float* wr = Wa + j * 16;
        float s = bz[j];
#pragma unroll
        for (int k = 0; k < 16; ++k) s += al[k] * wr[k];
        preA[(size_t)r * 1024 + j] = s;
    }
}

// ---------------- one-shot MFMA GEMM (f32 sources, bf16 staging)
__global__ __launch_bounds__(256) void gemm_mfma(
    const float* __restrict__ A, int lda,
    const float* __restrict__ B, int ldb,
    const float* __restrict__ bias,
    float* __restrict__ C, int ldc, int K)
{
    __shared__ unsigned short Alds[64 * 72];
    __shared__ unsigned short Blds[64 * 72];
    int t = threadIdx.x;
    int nb = blockIdx.x, mb = blockIdx.y;
    int w = t >> 6, l = t & 63, l15 = l & 15, kg = l >> 4;
    f32x4 acc[4] = {{0,0,0,0},{0,0,0,0},{0,0,0,0},{0,0,0,0}};
    int srow = t >> 2, skq = (t & 3) * 16;
    const float* Asrc = A + (size_t)(mb * 64 + srow) * lda + skq;
    const float* Bsrc = B + (size_t)(nb * 64 + srow) * ldb + skq;
    unsigned short* Adst = &Alds[srow * 72 + skq];
    unsigned short* Bdst = &Blds[srow * 72 + skq];
    for (int kt = 0; kt < K; kt += 64) {
        __syncthreads();
#pragma unroll
        for (int c = 0; c < 16; c += 4) {
            float4 va = *reinterpret_cast<const float4*>(Asrc + kt + c);
            float4 vb = *reinterpret_cast<const float4*>(Bsrc + kt + c);
            ushort4 oa, ob;
            oa.x = f2bf(va.x); oa.y = f2bf(va.y); oa.z = f2bf(va.z); oa.w = f2bf(va.w);
            ob.x = f2bf(vb.x); ob.y = f2bf(vb.y); ob.z = f2bf(vb.z); ob.w = f2bf(vb.w);
            *reinterpret_cast<ushort4*>(Adst + c) = oa;
            *reinterpret_cast<ushort4*>(Bdst + c) = ob;
        }
        __syncthreads();
#pragma unroll
        for (int ks = 0; ks < 2; ks++) {
            bf16x8 a = *reinterpret_cast<const bf16x8*>(&Alds[(w * 16 + l15) * 72 + ks * 32 + kg * 8]);
#pragma unroll
            for (int nt = 0; nt < 4; nt++) {
                bf16x8 b = *reinterpret_cast<const bf16x8*>(&Blds[(nt * 16 + l15) * 72 + ks * 32 + kg * 8]);
                acc[nt] = MFMA16(a, b, acc[nt], 0, 0, 0);
            }
        }
    }
#pragma unroll
    for (int nt = 0; nt < 4; nt++) {
        int n = nb * 64 + nt * 16 + l15;
        float bv = bias[n];
#pragma unroll
        for (int i = 0; i < 4; i++) {
            C[(size_t)(mb * 64 + w * 16 + kg * 4 + i) * ldc + n] = acc[nt][i] + bv;
        }
    }
}

// ---------------- row LN+elu in place (f32)
__global__ __launch_bounds__(256) void ln_elu_rows(
    float* __restrict__ X, const float* __restrict__ g, const float* __restrict__ bb)
{
    __shared__ float sbuf[256], qbuf[256];
    int r = blockIdx.x, t = threadIdx.x;
    float* row = X + (size_t)r * HIDDEN;
    float4 v = reinterpret_cast<const float4*>(row)[t];
    sbuf[t] = (v.x + v.y) + (v.z + v.w);
    qbuf[t] = (v.x * v.x + v.y * v.y) + (v.z * v.z + v.w * v.w);
    __syncthreads();
    for (int off = 128; off > 0; off >>= 1) {
        if (t < off) { sbuf[t] += sbuf[t + off]; qbuf[t] += qbuf[t + off]; }
        __syncthreads();
    }
    float mean = sbuf[0] / HIDDEN;
    float var = qbuf[0] / HIDDEN - mean * mean;
    float rstd = rsqrtf(var + 1e-5f);
    float4 gg = reinterpret_cast<const float4*>(g)[t];
    float4 bv = reinterpret_cast<const float4*>(bb)[t];
    float4 o;
    o.x = eluf((v.x - mean) * rstd * gg.x + bv.x);
    o.y = eluf((v.y - mean) * rstd * gg.y + bv.y);
    o.z = eluf((v.z - mean) * rstd * gg.z + bv.z);
    o.w = eluf((v.w - mean) * rstd * gg.w + bv.w);
    reinterpret_cast<float4*>(row)[t] = o;
}

__global__ __launch_bounds__(256) void k_copy_last(
    const float* __restrict__ feat63, const float* __restrict__ samp63,
    float* __restrict__ hlast, float* __restrict__ zlast)
{
    int i = blockIdx.x * 256 + threadIdx.x;
    if (i < BATCH * DETER) {
        int b = i / DETER, k = i % DETER;
        hlast[i] = feat63[(size_t)b * FEAT + k];
    }
    if (i < BATCH * STOCH) zlast[i] = samp63[i];
}

// ======================= persistent scan: 256 blocks x 512 threads =======================
struct ScanArgs {
    const unsigned short *Wz16, *Wih16, *Whh16, *Wph16, *Wpo16;
    const float *bih, *bhh, *b_post;
    const float *ln_in_g, *ln_in_b, *ln_post_g, *ln_post_b;
    const float *h0m;
    const uint8_t *reset;
    const float *noises;
    float *postsPreA, *priorsPreE, *samples, *feats;
    unsigned short *z16m, *x1b, *x2b, *h16u, *h16m0, *h16m1;
    float *x1parts, *x2parts;
    int *flags, *release;
};

__device__ __forceinline__ void ln_stats(const float* __restrict__ parts, float* stat, int tid) {
    if (tid < 32) {
        float s = 0.f, q = 0.f;
        for (int i = 0; i < 64; ++i) {
            union { unsigned long long u; float f[2]; } c;
            c.u = ldc_u64((const unsigned long long*)(parts + (size_t)(i * 32 + tid) * 2));
            s += c.f[0]; q += c.f[1];
        }
        float mean = s * (1.f / 1024.f);
        float var = q * (1.f / 1024.f) - mean * mean;
        stat[tid] = mean;
        stat[32 + tid] = rsqrtf(var + 1e-5f);
    }
}

// expects tid in [0,256)
__device__ __forceinline__ void ln_fill(unsigned short* Asm, const unsigned short* __restrict__ src,
                                        const float* __restrict__ g, const float* __restrict__ bb,
                                        const float* stat, int tid) {
    int row = tid & 31, kb = (tid >> 5) * 128;
    float mean = stat[row], rstd = stat[32 + row];
#pragma unroll 4
    for (int c = 0; c < 16; ++c) {
        int k = kb + c * 8;
        ushort4 u0 = ldc_us4(src + (size_t)row * 1024 + k);
        ushort4 u1 = ldc_us4(src + (size_t)row * 1024 + k + 4);
        float4 g0 = *reinterpret_cast<const float4*>(g + k);
        float4 g1 = *reinterpret_cast<const float4*>(g + k + 4);
        float4 b0 = *reinterpret_cast<const float4*>(bb + k);
        float4 b1 = *reinterpret_cast<const float4*>(bb + k + 4);
        ushort4 o0, o1;
        o0.x = f2bf(eluf((bf2f(u0.x) - mean) * rstd * g0.x + b0.x));
        o0.y = f2bf(eluf((bf2f(u0.y) - mean) * rstd * g0.y + b0.y));
        o0.z = f2bf(eluf((bf2f(u0.z) - mean) * rstd * g0.z + b0.z));
        o0.w = f2bf(eluf((bf2f(u0.w) - mean) * rstd * g0.w + b0.w));
        o1.x = f2bf(eluf((bf2f(u1.x) - mean) * rstd * g1.x + b1.x));
        o1.y = f2bf(eluf((bf2f(u1.y) - mean) * rstd * g1.y + b1.y));
        o1.z = f2bf(eluf((bf2f(u1.z) - mean) * rstd * g1.z + b1.z));
        o1.w = f2bf(eluf((bf2f(u1.w) - mean) * rstd * g1.w + b1.w));
        *reinterpret_cast<ushort4*>(Asm + row * 1032 + k) = o0;
        *reinterpret_cast<ushort4*>(Asm + row * 1032 + k + 4) = o1;
    }
}

__global__ __launch_bounds__(512, 1) void k_scan(ScanArgs a) {
    // 93184 B > 80 KiB -> 1 block/CU; grid 256 <= 256 CUs -> all co-resident.
    __shared__ char smem[93184];
    unsigned short* Asm = (unsigned short*)smem;       // 66048 B: 32 x 1032 bf16
    float* cbuf  = (float*)(smem + 66048);             // P2: 8x768 f32 (24576 B); P1/P3/P4: first 8 KB
    float* stat  = (float*)(smem + 66048 + 8192);      // P4/ln path (r12 position, 512 B)
    float* stat2 = (float*)(smem + 90624);             // P2 LN stats (512 B)
    float* hbuf  = (float*)(smem + 91136);             // P2 combine out (2048 B)

    const int bid = blockIdx.x;
    const int tid = threadIdx.x;
    const int w = tid >> 6, l = tid & 63, l15 = l & 15, kg = l >> 4;
    int epoch = 0;

    for (int t = 0; t < NSTEP; ++t) {
        const float* preA_t = a.postsPreA + (size_t)t * 32768;
        const float* preE_t = a.priorsPreE + (size_t)t * 32768;
        float* posts_t = a.postsPreA + (size_t)t * 32768;
        float* samples_t = a.samples + (size_t)t * 16384;
        float* feats_t = a.feats + (size_t)t * 81920;
        const float* featsPrev = a.feats + (size_t)(t - 1) * 81920;
        const unsigned short* h16cur = (t & 1) ? a.h16m1 : a.h16m0;
        unsigned short* h16nxt = (t & 1) ? a.h16m0 : a.h16m1;

        // ---------- P1 (r12 verbatim, tid<256): x1 = preA + (m z)@Wz^T, 64 blocks
        if (bid < 64) {
            int j0 = bid * 16;
            if (tid < 256) {
                const unsigned short* A0 = a.z16m + l15 * 512 + w * 128 + kg * 8;
                const unsigned short* A1 = A0 + 16 * 512;
                const unsigned short* Bp = a.Wz16 + (size_t)(j0 + l15) * 512 + w * 128 + kg * 8;
                f32x4 c0 = {0,0,0,0}, c1 = {0,0,0,0};
#pragma unroll
                for (int ks = 0; ks < 4; ++ks) {
                    bf16x8 b = *reinterpret_cast<const bf16x8*>(Bp + ks * 32);
                    c0 = MFMA16(ldc_bf8(A0 + ks * 32), b, c0, 0, 0, 0);
                    c1 = MFMA16(ldc_bf8(A1 + ks * 32), b, c1, 0, 0, 0);
                }
#pragma unroll
                for (int i = 0; i < 4; ++i) {
                    cbuf[w * 512 + (kg * 4 + i) * 16 + l15] = c0[i];
                    cbuf[w * 512 + (16 + kg * 4 + i) * 16 + l15] = c1[i];
                }
            }
            __syncthreads();
            if (tid < 256) {
                int r = tid >> 3, c2 = (tid & 7) * 2;
                int base = r * 16 + c2;
                float v0 = cbuf[base] + cbuf[512 + base] + cbuf[1024 + base] + cbuf[1536 + base]
                         + preA_t[r * 1024 + j0 + c2];
                float v1 = cbuf[base + 1] + cbuf[512 + base + 1] + cbuf[1024 + base + 1] + cbuf[1536 + base + 1]
                         + preA_t[r * 1024 + j0 + c2 + 1];
                unsigned short u0 = f2bf(v0), u1 = f2bf(v1);
                stc_u32((unsigned*)(a.x1b + (size_t)r * 1024 + j0 + c2),
                        (unsigned)u0 | ((unsigned)u1 << 16));
                float w0 = bf2f(u0), w1 = bf2f(u1);
                float s = w0 + w1, q = w0 * w0 + w1 * w1;
                s += __shfl_xor(s, 1); q += __shfl_xor(q, 1);
                s += __shfl_xor(s, 2); q += __shfl_xor(q, 2);
                s += __shfl_xor(s, 4); q += __shfl_xor(q, 4);
                if ((tid & 7) == 0) {
                    union { float f[2]; unsigned long long u; } pu;
                    pu.f[0] = s; pu.f[1] = q;
                    stc_u64((unsigned long long*)(a.x1parts + ((size_t)bid * 32 + r) * 2), pu.u);
                }
            }
        }
        epoch++; gbar3(a.flags, a.release, epoch);

        // ---------- P2 (K-split, 8 waves): gates MFMA + combine, 128 blocks
        if (bid < 128) {
            int j0 = bid * 16;
            ln_stats(a.x1parts, stat2, tid);
            __syncthreads();
            if (tid < 256) ln_fill(Asm, a.x1b, a.ln_in_g, a.ln_in_b, stat2, tid);
            __syncthreads();
            f32x4 cr = {0,0,0,0}, cu = {0,0,0,0}, cn = {0,0,0,0};
            if (w < 4) {
                // gi: rowgrp = w&1, K-half = w>>1 (512 each), za from LDS
                int rowgrp = w & 1, kh = w >> 1;
                const unsigned short* ap = Asm + (rowgrp * 16 + l15) * 1032 + kh * 512 + kg * 8;
                const unsigned short* br = a.Wih16 + (size_t)(j0 + l15) * 1024 + kh * 512 + kg * 8;
                const unsigned short* bu = br + (size_t)2048 * 1024;
                const unsigned short* bn = bu + (size_t)2048 * 1024;
#pragma unroll 4
                for (int ks = 0; ks < 16; ++ks) {
                    bf16x8 av = *reinterpret_cast<const bf16x8*>(ap + ks * 32);
                    cr = MFMA16(av, *reinterpret_cast<const bf16x8*>(br + ks * 32), cr, 0, 0, 0);
                    cu = MFMA16(av, *reinterpret_cast<const bf16x8*>(bu + ks * 32), cu, 0, 0, 0);
                    cn = MFMA16(av, *reinterpret_cast<const bf16x8*>(bn + ks * 32), cn, 0, 0, 0);
                }
            } else {
                // gh: rowgrp = (w-4)&1, K-half = (w-4)>>1 (1024 each); h premasked
                int idx = w - 4, rowgrp = idx & 1, kh = idx >> 1;
                const unsigned short* hp = h16cur + (size_t)(rowgrp * 16 + l15) * 2048 + kh * 1024 + kg * 8;
                const unsigned short* br = a.Whh16 + (size_t)(j0 + l15) * 2048 + kh * 1024 + kg * 8;
                const unsigned short* bu = br + (size_t)2048 * 2048;
                const unsigned short* bn = bu + (size_t)2048 * 2048;
#pragma unroll 4
                for (int ks = 0; ks < 32; ++ks) {
                    bf16x8 av = ldc_bf8(hp + ks * 32);
                    cr = MFMA16(av, *reinterpret_cast<const bf16x8*>(br + ks * 32), cr, 0, 0, 0);
                    cu = MFMA16(av, *reinterpret_cast<const bf16x8*>(bu + ks * 32), cu, 0, 0, 0);
                    cn = MFMA16(av, *reinterpret_cast<const bf16x8*>(bn + ks * 32), cn, 0, 0, 0);
                }
            }
#pragma unroll
            for (int i = 0; i < 4; ++i) {
                int o = (kg * 4 + i) * 16 + l15;
                cbuf[w * 768 + 0 * 256 + o] = cr[i];
                cbuf[w * 768 + 1 * 256 + o] = cu[i];
                cbuf[w * 768 + 2 * 256 + o] = cn[i];
            }
            __syncthreads();
            // combine: 512 threads, one (row,col) each
            {
                int row = tid >> 4, col = tid & 15;
                int rowgrp = row >> 4, rr = row & 15;
                int o = rr * 16 + col;
                int j = j0 + col;
                float gr = cbuf[rowgrp * 768 + 0 * 256 + o] + cbuf[(2 + rowgrp) * 768 + 0 * 256 + o] + a.bih[j];
                float gu = cbuf[rowgrp * 768 + 1 * 256 + o] + cbuf[(2 + rowgrp) * 768 + 1 * 256 + o] + a.bih[j + 2048];
                float gn = cbuf[rowgrp * 768 + 2 * 256 + o] + cbuf[(2 + rowgrp) * 768 + 2 * 256 + o] + a.bih[j + 4096];
                float hr = cbuf[(4 + rowgrp) * 768 + 0 * 256 + o] + cbuf[(6 + rowgrp) * 768 + 0 * 256 + o] + a.bhh[j];
                float hu = cbuf[(4 + rowgrp) * 768 + 1 * 256 + o] + cbuf[(6 + rowgrp) * 768 + 1 * 256 + o] + a.bhh[j + 2048];
                float hn = cbuf[(4 + rowgrp) * 768 + 2 * 256 + o] + cbuf[(6 + rowgrp) * 768 + 2 * 256 + o] + a.bhh[j + 4096];
                float r_ = sigf(gr + hr), u_ = sigf(gu + hu);
                float cand = tanhf(gn + r_ * hn);
                float m = a.reset[t * 32 + row] ? 0.f : 1.f;
                float hpv = (t == 0) ? a.h0m[(size_t)row * 2048 + j]
                                     : ldc_f32(featsPrev + (size_t)row * 2560 + j);
                hbuf[row * 16 + col] = (1.f - u_) * cand + u_ * (m * hpv);
            }
            __syncthreads();
            if (tid < 256) {
                int b = tid >> 3, c2 = (tid & 7) * 2;
                float h0v = hbuf[b * 16 + c2], h1v = hbuf[b * 16 + c2 + 1];
                int j = j0 + c2;
                union { float f[2]; unsigned long long u; } fu;
                fu.f[0] = h0v; fu.f[1] = h1v;
                stc_u64((unsigned long long*)(feats_t + (size_t)b * 2560 + j), fu.u);
                unsigned short g0 = f2bf(h0v), g1 = f2bf(h1v);
                stc_u32((unsigned*)(a.h16u + (size_t)b * 2048 + j),
                        (unsigned)g0 | ((unsigned)g1 << 16));
                float mn = (t < 63) ? (a.reset[(t + 1) * 32 + b] ? 0.f : 1.f) : 1.f;
                unsigned short n0 = f2bf(h0v * mn), n1 = f2bf(h1v * mn);
                stc_u32((unsigned*)(h16nxt + (size_t)b * 2048 + j),
                        (unsigned)n0 | ((unsigned)n1 << 16));
            }
        }
        epoch++; gbar3(a.flags, a.release, epoch);

        // ---------- P3 (r12 verbatim, tid<256): x2 = preE + h@Wph^T, 64 blocks
        if (bid < 64) {
            int j0 = bid * 16;
            if (tid < 256) {
                const unsigned short* A0 = a.h16u + l15 * 2048 + w * 512 + kg * 8;
                const unsigned short* A1 = A0 + 16 * 2048;
                const unsigned short* Bp = a.Wph16 + (size_t)(j0 + l15) * 2048 + w * 512 + kg * 8;
                f32x4 c0 = {0,0,0,0}, c1 = {0,0,0,0};
#pragma unroll 8
                for (int ks = 0; ks < 16; ++ks) {
                    bf16x8 b = *reinterpret_cast<const bf16x8*>(Bp + ks * 32);
                    c0 = MFMA16(ldc_bf8(A0 + ks * 32), b, c0, 0, 0, 0);
                    c1 = MFMA16(ldc_bf8(A1 + ks * 32), b, c1, 0, 0, 0);
                }
#pragma unroll
                for (int i = 0; i < 4; ++i) {
                    cbuf[w * 512 + (kg * 4 + i) * 16 + l15] = c0[i];
                    cbuf[w * 512 + (16 + kg * 4 + i) * 16 + l15] = c1[i];
                }
            }
            __syncthreads();
            if (tid < 256) {
                int r = tid >> 3, c2 = (tid & 7) * 2;
                int base = r * 16 + c2;
                float v0 = cbuf[base] + cbuf[512 + base] + cbuf[1024 + base] + cbuf[1536 + base]
                         + preE_t[r * 1024 + j0 + c2];
                float v1 = cbuf[base + 1] + cbuf[512 + base + 1] + cbuf[1024 + base + 1] + cbuf[1536 + base + 1]
                         + preE_t[r * 1024 + j0 + c2 + 1];
                unsigned short u0 = f2bf(v0), u1 = f2bf(v1);
                stc_u32((unsigned*)(a.x2b + (size_t)r * 1024 + j0 + c2),
                        (unsigned)u0 | ((unsigned)u1 << 16));
                float w0 = bf2f(u0), w1 = bf2f(u1);
                float s = w0 + w1, q = w0 * w0 + w1 * w1;
                s += __shfl_xor(s, 1); q += __shfl_xor(q, 1);
                s += __shfl_xor(s, 2); q += __shfl_xor(q, 2);
                s += __shfl_xor(s, 4); q += __shfl_xor(q, 4);
                if ((tid & 7) == 0) {
                    union { float f[2]; unsigned long long u; } pu;
                    pu.f[0] = s; pu.f[1] = q;
                    stc_u64((unsigned long long*)(a.x2parts + ((size_t)bid * 32 + r) * 2), pu.u);
                }
            }
        }
        epoch++; gbar3(a.flags, a.release, epoch);

        // ---------- P4 (r12 verbatim, tid<256): post MFMA + sample, 32 blocks
        if (bid < 32) {
            int j0 = bid * 16;
            ln_stats(a.x2parts, stat, tid);
            __syncthreads();
            if (tid < 256) ln_fill(Asm, a.x2b, a.ln_post_g, a.ln_post_b, stat, tid);
            __syncthreads();
            if (tid < 256) {
                int tile = w >> 1, mt = w & 1;
                const unsigned short* ap = Asm + (mt * 16 + l15) * 1032 + kg * 8;
                int n = (tile == 0) ? (j0 + l15) : (512 + j0 + l15);
                const unsigned short* Bp = a.Wpo16 + (size_t)n * 1024 + kg * 8;
                f32x4 c = {0,0,0,0};
#pragma unroll 8
                for (int ks = 0; ks < 32; ++ks) {
                    c = MFMA16(*reinterpret_cast<const bf16x8*>(ap + ks * 32),
                               *reinterpret_cast<const bf16x8*>(Bp + ks * 32), c, 0, 0, 0);
                }
#pragma unroll
                for (int i = 0; i < 4; ++i)
                    cbuf[(tile * 2 + mt) * 256 + (kg * 4 + i) * 16 + l15] = c[i];
            }
            __syncthreads();
            if (tid < 256) {
                int b = tid >> 3, c2 = (tid & 7) * 2;
                int j = j0 + c2;
                int ib = (b >> 4) * 256 + (b & 15) * 16;
                float pm0 = cbuf[ib + c2] + a.b_post[j];
                float pm1 = cbuf[ib + c2 + 1] + a.b_post[j + 1];
                float ps0 = cbuf[512 + ib + c2] + a.b_post[512 + j];
                float ps1 = cbuf[512 + ib + c2 + 1] + a.b_post[512 + j + 1];
                posts_t[(size_t)b * 1024 + j] = pm0;
                posts_t[(size_t)b * 1024 + j + 1] = pm1;
                posts_t[(size_t)b * 1024 + 512 + j] = ps0;
                posts_t[(size_t)b * 1024 + 512 + j + 1] = ps1;
                float sp0 = fmaxf(ps0, 0.f) + log1pf(expf(-fabsf(ps0)));
                float sp1 = fmaxf(ps1, 0.f) + log1pf(expf(-fabsf(ps1)));
                float n0v = a.noises[(size_t)t * 16384 + b * 512 + j];
                float n1v = a.noises[(size_t)t * 16384 + b * 512 + j + 1];
                float smp0 = pm0 + (sp0 + 0.1f) * n0v;
                float smp1 = pm1 + (sp1 + 0.1f) * n1v;
                samples_t[(size_t)b * 512 + j] = smp0;
                samples_t[(size_t)b * 512 + j + 1] = smp1;
                feats_t[(size_t)b * 2560 + 2048 + j] = smp0;
                feats_t[(size_t)b * 2560 + 2048 + j + 1] = smp1;
                float mn = (t < 63) ? (a.reset[(t + 1) * 32 + b] ? 0.f : 1.f) : 1.f;
                unsigned short z0_ = f2bf(smp0 * mn), z1_ = f2bf(smp1 * mn);
                stc_u32((unsigned*)(a.z16m + (size_t)b * 512 + j),
                        (unsigned)z0_ | ((unsigned)z1_ << 16));
            }
        }
        epoch++; gbar3(a.flags, a.release, epoch);
    }
}

// ws byte offsets (r12 layout)
#define WS_WZ16   ((size_t)0)
#define WS_WIH16  ((size_t)1048576)
#define WS_WHH16  ((size_t)13631488)
#define WS_WPH16  ((size_t)38797312)
#define WS_WPO16  ((size_t)42991616)
#define WS_Z16M   ((size_t)45088768)
#define WS_H16M0  ((size_t)45121536)
#define WS_H16M1  ((size_t)45252608)
#define WS_H16U   ((size_t)45383680)
#define WS_H0M    ((size_t)45514752)
#define WS_X1B    ((size_t)45776896)
#define WS_X2B    ((size_t)45842432)
#define WS_X1P    ((size_t)45907968)
#define WS_X2P    ((size_t)45924352)
#define WS_FLAGS  ((size_t)45940736)
#define WS_REL    ((size_t)45973504)
#define WS_PRX    WS_WIH16

extern "C" void kernel_launch(void* const* d_in, const int* in_sizes, int n_in,
                              void* d_out, int out_size, void* d_ws, size_t ws_size,
                              hipStream_t stream)
{
    (void)in_sizes; (void)n_in; (void)out_size; (void)ws_size;
    const float*   embed  = (const float*)d_in[0];
    const float*   action = (const float*)d_in[1];
    const uint8_t* reset  = (const uint8_t*)d_in[2];
    const float*   h0     = (const float*)d_in[3];
    const float*   z0     = (const float*)d_in[4];
    const float*   noises = (const float*)d_in[5];
    const float*   W_z    = (const float*)d_in[6];
    const float*   b_z    = (const float*)d_in[7];
    const float*   W_a    = (const float*)d_in[8];
    const float*   ln_in_g = (const float*)d_in[9];
    const float*   ln_in_b = (const float*)d_in[10];
    const float*   Wih    = (const float*)d_in[11];
    const float*   Whh    = (const float*)d_in[12];
    const float*   bih    = (const float*)d_in[13];
    const float*   bhh    = (const float*)d_in[14];
    const float*   W_ph   = (const float*)d_in[15];
    const float*   b_ph   = (const float*)d_in[16];
    const float*   W_pe   = (const float*)d_in[17];
    const float*   ln_post_g = (const float*)d_in[18];
    const float*   ln_post_b = (const float*)d_in[19];
    const float*   W_post = (const float*)d_in[20];
    const float*   b_post = (const float*)d_in[21];
    const float*   W_prh  = (const float*)d_in[22];
    const float*   b_prh  = (const float*)d_in[23];
    const float*   ln_pr_g = (const float*)d_in[24];
    const float*   ln_pr_b = (const float*)d_in[25];
    const float*   W_pr   = (const float*)d_in[26];
    const float*   b_pr   = (const float*)d_in[27];

    float* out     = (float*)d_out;
    float* priors  = out;                  // preE lives here during scan
    float* posts   = out + 2097152;        // preA lives here during scan
    float* samples = out + 4194304;
    float* feats   = out + 5242880;
    float* hlast   = out + 10485760;
    float* zlast   = out + 10551296;

    char* ws = (char*)d_ws;
    unsigned short* Wz16  = (unsigned short*)(ws + WS_WZ16);
    unsigned short* Wih16 = (unsigned short*)(ws + WS_WIH16);
    unsigned short* Whh16 = (unsigned short*)(ws + WS_WHH16);
    unsigned short* Wph16 = (unsigned short*)(ws + WS_WPH16);
    unsigned short* Wpo16 = (unsigned short*)(ws + WS_WPO16);
    unsigned short* z16m  = (unsigned short*)(ws + WS_Z16M);
    unsigned short* h16m0 = (unsigned short*)(ws + WS_H16M0);
    unsigned short* h16m1 = (unsigned short*)(ws + WS_H16M1);
    unsigned short* h16u  = (unsigned short*)(ws + WS_H16U);
    float*          h0m   = (float*)(ws + WS_H0M);
    unsigned short* x1b   = (unsigned short*)(ws + WS_X1B);
    unsigned short* x2b   = (unsigned short*)(ws + WS_X2B);
    float*          x1p   = (float*)(ws + WS_X1P);
    float*          x2p   = (float*)(ws + WS_X2P);
    int*            flags = (int*)(ws + WS_FLAGS);
    int*            release = (int*)(ws + WS_REL);
    float*          prx   = (float*)(ws + WS_PRX);

    dim3 blk(256);

    k_cvt_all<<<dim3(22016), blk, 0, stream>>>(W_z, Wz16, Wih, Wih16, Whh, Whh16,
                                               W_ph, Wph16, W_post, Wpo16);
    k_setup<<<dim3(80), blk, 0, stream>>>(h0, z0, reset, h0m, h16m0, z16m, flags);

    // preA -> posts region ; preE -> priors region
    k_preA<<<dim3(2048), blk, 0, stream>>>(action, W_a, b_z, posts);
    gemm_mfma<<<dim3(16, 32), blk, 0, stream>>>(embed, EMBED_D, W_pe, EMBED_D, b_ph,
                                                priors, HIDDEN, EMBED_D);

    ScanArgs sa;
    sa.Wz16 = Wz16; sa.Wih16 = Wih16; sa.Whh16 = Whh16; sa.Wph16 = Wph16; sa.Wpo16 = Wpo16;
    sa.bih = bih; sa.bhh = bhh; sa.b_post = b_post;
    sa.ln_in_g = ln_in_g; sa.ln_in_b = ln_in_b; sa.ln_post_g = ln_post_g; sa.ln_post_b = ln_post_b;
    sa.h0m = h0m; sa.reset = reset; sa.noises = noises;
    sa.postsPreA = posts; sa.priorsPreE = priors; sa.samples = samples; sa.feats = feats;
    sa.z16m = z16m; sa.x1b = x1b; sa.x2b = x2b; sa.h16u = h16u;
    sa.h16m0 = h16m0; sa.h16m1 = h16m1;
    sa.x1parts = x1p; sa.x2parts = x2p;
    sa.flags = flags; sa.release = release;

    // Plain launch: 256 blocks x 512 threads; LDS 93184 B -> 1 block/CU, all co-resident.
    k_scan<<<dim3(NBLK), dim3(512), 0, stream>>>(sa);

    // prior chain
    gemm_mfma<<<dim3(16, 32), blk, 0, stream>>>(feats, FEAT, W_prh, DETER, b_prh,
                                                prx, HIDDEN, DETER);
    ln_elu_rows<<<dim3(2048), blk, 0, stream>>>(prx, ln_pr_g, ln_pr_b);
    gemm_mfma<<<dim3(16, 32), blk, 0, stream>>>(prx, HIDDEN, W_pr, HIDDEN, b_pr,
                                                priors, HIDDEN, HIDDEN);

    k_copy_last<<<dim3(256), blk, 0, stream>>>(
        feats + (size_t)(NSTEP - 1) * BATCH * FEAT,
        samples + (size_t)(NSTEP - 1) * BATCH * STOCH,
        hlast, zlast);
}

// Round 15
// 4353.304 us; speedup vs baseline: 1.7379x; 1.0361x over previous
//
#include <hip/hip_runtime.h>
#include <hip/hip_bf16.h>
#include <stdint.h>

#define NSTEP 64
#define BATCH 32
#define EMBED_D 1536
#define ACT_D 16
#define DETER 2048
#define STOCH 512
#define HIDDEN 1024
#define FEAT 2560
#define NBLK 256

typedef __attribute__((ext_vector_type(8))) short bf16x8;
typedef __attribute__((ext_vector_type(4))) float f32x4;

#define MFMA16 __builtin_amdgcn_mfma_f32_16x16x32_bf16
#define AGENT __HIP_MEMORY_SCOPE_AGENT

__device__ __forceinline__ float eluf(float x) { return x > 0.f ? x : expf(x) - 1.f; }
__device__ __forceinline__ float sigf(float x) { return 1.f / (1.f + expf(-x)); }
__device__ __forceinline__ unsigned short f2bf(float f) {
    __hip_bfloat16 h = __float2bfloat16(f);
    return __builtin_bit_cast(unsigned short, h);
}
__device__ __forceinline__ float bf2f(unsigned short u) {
    unsigned v = ((unsigned)u) << 16;
    return __builtin_bit_cast(float, v);
}

// ---- sc1 (agent-scope, fence-free) access helpers — r5/r12 proven data plane
__device__ __forceinline__ void stc_u32(unsigned* p, unsigned v) {
    __hip_atomic_store(p, v, __ATOMIC_RELAXED, AGENT);
}
__device__ __forceinline__ void stc_u64(unsigned long long* p, unsigned long long v) {
    __hip_atomic_store(p, v, __ATOMIC_RELAXED, AGENT);
}
__device__ __forceinline__ unsigned long long ldc_u64(const unsigned long long* p) {
    return __hip_atomic_load(p, __ATOMIC_RELAXED, AGENT);
}
__device__ __forceinline__ float ldc_f32(const float* p) {
    return __hip_atomic_load(p, __ATOMIC_RELAXED, AGENT);
}
__device__ __forceinline__ int ldc_i32(const int* p) {
    return __hip_atomic_load(p, __ATOMIC_RELAXED, AGENT);
}
__device__ __forceinline__ void stc_i32(int* p, int v) {
    __hip_atomic_store(p, v, __ATOMIC_RELAXED, AGENT);
}
__device__ __forceinline__ bf16x8 ldc_bf8(const unsigned short* p) {
    union { unsigned long long q[2]; bf16x8 v; } u;
    u.q[0] = ldc_u64((const unsigned long long*)p);
    u.q[1] = ldc_u64((const unsigned long long*)(p + 4));
    return u.v;
}
__device__ __forceinline__ ushort4 ldc_us4(const unsigned short* p) {
    unsigned long long q = ldc_u64((const unsigned long long*)p);
    return __builtin_bit_cast(ushort4, q);
}

// ---- flag-tree grid barrier, 32-way replicated release (r10/r12-verified)
__device__ __forceinline__ void gbar3(int* flags, int* release, int epoch) {
    asm volatile("s_waitcnt vmcnt(0)" ::: "memory");
    __syncthreads();
    if (blockIdx.x == 0) {
        int tid = threadIdx.x;
        if (tid >= 1 && tid < NBLK) {
            while (ldc_i32(&flags[tid * 32]) < epoch) __builtin_amdgcn_s_sleep(4);
        }
        asm volatile("" ::: "memory");
        __syncthreads();
        if (tid < 32) stc_i32(&release[tid * 32], epoch);
    } else {
        if (threadIdx.x == 0) {
            stc_i32(&flags[blockIdx.x * 32], epoch);
            int* rel = &release[(blockIdx.x & 31) * 32];
            while (ldc_i32(rel) < epoch) __builtin_amdgcn_s_sleep(4);
        }
        asm volatile("" ::: "memory");
        __syncthreads();
    }
}

// ---------------- all weight conversions in one kernel (bf16)
__global__ __launch_bounds__(256) void k_cvt_all(
    const float* __restrict__ s0, unsigned short* __restrict__ d0,
    const float* __restrict__ s1, unsigned short* __restrict__ d1,
    const float* __restrict__ s2, unsigned short* __restrict__ d2,
    const float* __restrict__ s3, unsigned short* __restrict__ d3,
    const float* __restrict__ s4, unsigned short* __restrict__ d4)
{
    long long e = ((long long)blockIdx.x * 256 + threadIdx.x) * 4;
    const float* src; unsigned short* dst; long long off;
    if (e < 524288)        { src = s0; dst = d0; off = e; }
    else if (e < 6815744)  { src = s1; dst = d1; off = e - 524288; }
    else if (e < 19398656) { src = s2; dst = d2; off = e - 6815744; }
    else if (e < 21495808) { src = s3; dst = d3; off = e - 19398656; }
    else if (e < 22544384) { src = s4; dst = d4; off = e - 21495808; }
    else return;
    float4 v = *reinterpret_cast<const float4*>(src + off);
    ushort4 o;
    o.x = f2bf(v.x); o.y = f2bf(v.y); o.z = f2bf(v.z); o.w = f2bf(v.w);
    *reinterpret_cast<ushort4*>(dst + off) = o;
}

// ---------------- setup: premasked h0 (f32+bf16), premasked z0 (bf16), flags=0
__global__ __launch_bounds__(256) void k_setup(
    const float* __restrict__ h0, const float* __restrict__ z0,
    const uint8_t* __restrict__ reset0,
    float* __restrict__ h0m, unsigned short* __restrict__ h16m0,
    unsigned short* __restrict__ z16m, int* __restrict__ flags)
{
    int gid = blockIdx.x * 256 + threadIdx.x;
    int idx = gid * 4;
    if (idx < BATCH * DETER) {
        int b = idx >> 11;
        float m = reset0[b] ? 0.f : 1.f;
        float4 v = *reinterpret_cast<const float4*>(h0 + idx);
        v.x *= m; v.y *= m; v.z *= m; v.w *= m;
        *reinterpret_cast<float4*>(h0m + idx) = v;
        ushort4 o;
        o.x = f2bf(v.x); o.y = f2bf(v.y); o.z = f2bf(v.z); o.w = f2bf(v.w);
        *reinterpret_cast<ushort4*>(h16m0 + idx) = o;
    } else if (idx < BATCH * DETER + BATCH * STOCH) {
        int zi = idx - BATCH * DETER;
        int b = zi >> 9;
        float m = reset0[b] ? 0.f : 1.f;
        float4 v = *reinterpret_cast<const float4*>(z0 + zi);
        ushort4 o;
        o.x = f2bf(v.x * m); o.y = f2bf(v.y * m); o.z = f2bf(v.z * m); o.w = f2bf(v.w * m);
        *reinterpret_cast<ushort4*>(z16m + zi) = o;
    }
    if (gid < 9216) flags[gid] = 0;
}

// ---------------- preA[r][j] = b_z[j] + action[r]@Wa[j]  (K=16)
__global__ __launch_bounds__(256) void k_preA(
    const float* __restrict__ action, const float* __restrict__ Wa,
    const float* __restrict__ bz, float* __restrict__ preA)
{
    __shared__ float al[16];
    int r = blockIdx.x, t = threadIdx.x;
    if (t < 16) al[t] = action[r * 16 + t];
    __syncthreads();
#pragma unroll
    for (int c = 0; c < 4; ++c) {
        int j = t + c * 256;
        const float* wr = Wa + j * 16;
        float s = bz[j];
#pragma unroll
        for (int k = 0; k < 16; ++k) s += al[k] * wr[k];
        preA[(size_t)r * 1024 + j] = s;
    }
}

// ---------------- one-shot MFMA GEMM (f32 sources, bf16 staging)
__global__ __launch_bounds__(256) void gemm_mfma(
    const float* __restrict__ A, int lda,
    const float* __restrict__ B, int ldb,
    const float* __restrict__ bias,
    float* __restrict__ C, int ldc, int K)
{
    __shared__ unsigned short Alds[64 * 72];
    __shared__ unsigned short Blds[64 * 72];
    int t = threadIdx.x;
    int nb = blockIdx.x, mb = blockIdx.y;
    int w = t >> 6, l = t & 63, l15 = l & 15, kg = l >> 4;
    f32x4 acc[4] = {{0,0,0,0},{0,0,0,0},{0,0,0,0},{0,0,0,0}};
    int srow = t >> 2, skq = (t & 3) * 16;
    const float* Asrc = A + (size_t)(mb * 64 + srow) * lda + skq;
    const float* Bsrc = B + (size_t)(nb * 64 + srow) * ldb + skq;
    unsigned short* Adst = &Alds[srow * 72 + skq];
    unsigned short* Bdst = &Blds[srow * 72 + skq];
    for (int kt = 0; kt < K; kt += 64) {
        __syncthreads();
#pragma unroll
        for (int c = 0; c < 16; c += 4) {
            float4 va = *reinterpret_cast<const float4*>(Asrc + kt + c);
            float4 vb = *reinterpret_cast<const float4*>(Bsrc + kt + c);
            ushort4 oa, ob;
            oa.x = f2bf(va.x); oa.y = f2bf(va.y); oa.z = f2bf(va.z); oa.w = f2bf(va.w);
            ob.x = f2bf(vb.x); ob.y = f2bf(vb.y); ob.z = f2bf(vb.z); ob.w = f2bf(vb.w);
            *reinterpret_cast<ushort4*>(Adst + c) = oa;
            *reinterpret_cast<ushort4*>(Bdst + c) = ob;
        }
        __syncthreads();
#pragma unroll
        for (int ks = 0; ks < 2; ks++) {
            bf16x8 a = *reinterpret_cast<const bf16x8*>(&Alds[(w * 16 + l15) * 72 + ks * 32 + kg * 8]);
#pragma unroll
            for (int nt = 0; nt < 4; nt++) {
                bf16x8 b = *reinterpret_cast<const bf16x8*>(&Blds[(nt * 16 + l15) * 72 + ks * 32 + kg * 8]);
                acc[nt] = MFMA16(a, b, acc[nt], 0, 0, 0);
            }
        }
    }
#pragma unroll
    for (int nt = 0; nt < 4; nt++) {
        int n = nb * 64 + nt * 16 + l15;
        float bv = bias[n];
#pragma unroll
        for (int i = 0; i < 4; i++) {
            C[(size_t)(mb * 64 + w * 16 + kg * 4 + i) * ldc + n] = acc[nt][i] + bv;
        }
    }
}

// ---------------- row LN+elu in place (f32)
__global__ __launch_bounds__(256) void ln_elu_rows(
    float* __restrict__ X, const float* __restrict__ g, const float* __restrict__ bb)
{
    __shared__ float sbuf[256], qbuf[256];
    int r = blockIdx.x, t = threadIdx.x;
    float* row = X + (size_t)r * HIDDEN;
    float4 v = reinterpret_cast<const float4*>(row)[t];
    sbuf[t] = (v.x + v.y) + (v.z + v.w);
    qbuf[t] = (v.x * v.x + v.y * v.y) + (v.z * v.z + v.w * v.w);
    __syncthreads();
    for (int off = 128; off > 0; off >>= 1) {
        if (t < off) { sbuf[t] += sbuf[t + off]; qbuf[t] += qbuf[t + off]; }
        __syncthreads();
    }
    float mean = sbuf[0] / HIDDEN;
    float var = qbuf[0] / HIDDEN - mean * mean;
    float rstd = rsqrtf(var + 1e-5f);
    float4 gg = reinterpret_cast<const float4*>(g)[t];
    float4 bv = reinterpret_cast<const float4*>(bb)[t];
    float4 o;
    o.x = eluf((v.x - mean) * rstd * gg.x + bv.x);
    o.y = eluf((v.y - mean) * rstd * gg.y + bv.y);
    o.z = eluf((v.z - mean) * rstd * gg.z + bv.z);
    o.w = eluf((v.w - mean) * rstd * gg.w + bv.w);
    reinterpret_cast<float4*>(row)[t] = o;
}

__global__ __launch_bounds__(256) void k_copy_last(
    const float* __restrict__ feat63, const float* __restrict__ samp63,
    float* __restrict__ hlast, float* __restrict__ zlast)
{
    int i = blockIdx.x * 256 + threadIdx.x;
    if (i < BATCH * DETER) {
        int b = i / DETER, k = i % DETER;
        hlast[i] = feat63[(size_t)b * FEAT + k];
    }
    if (i < BATCH * STOCH) zlast[i] = samp63[i];
}

// ======================= persistent scan: 256 blocks x 512 threads =======================
struct ScanArgs {
    const unsigned short *Wz16, *Wih16, *Whh16, *Wph16, *Wpo16;
    const float *bih, *bhh, *b_post;
    const float *ln_in_g, *ln_in_b, *ln_post_g, *ln_post_b;
    const float *h0m;
    const uint8_t *reset;
    const float *noises;
    float *postsPreA, *priorsPreE, *samples, *feats;
    unsigned short *z16m, *x1b, *x2b, *h16u, *h16m0, *h16m1;
    float *x1parts, *x2parts;
    int *flags, *release;
};

// parallel stats: 512 threads load 4 records each, 2-level LDS reduce.
// scratch: >=1024 floats. caller must __syncthreads() after.
__device__ __forceinline__ void ln_stats2(const float* __restrict__ parts, float* stat,
                                          float* scratch, int tid) {
    int row = tid & 31, grp = tid >> 5;   // 16 groups x 4 records
    float s = 0.f, q = 0.f;
#pragma unroll
    for (int i = 0; i < 4; ++i) {
        union { unsigned long long u; float f[2]; } c;
        c.u = ldc_u64((const unsigned long long*)parts + (size_t)(grp * 4 + i) * 32 + row);
        s += c.f[0]; q += c.f[1];
    }
    scratch[row * 16 + grp] = s;
    scratch[512 + row * 16 + grp] = q;
    __syncthreads();
    if (tid < 32) {
        float ss = 0.f, qq = 0.f;
#pragma unroll
        for (int g = 0; g < 16; ++g) {
            ss += scratch[tid * 16 + g];
            qq += scratch[512 + tid * 16 + g];
        }
        float mean = ss * (1.f / 1024.f);
        float var = qq * (1.f / 1024.f) - mean * mean;
        stat[tid] = mean;
        stat[32 + tid] = rsqrtf(var + 1e-5f);
    }
}

// LN+elu fill over 512 threads (r13-verified): row = tid&31, 64-col group per thread
__device__ __forceinline__ void ln_fill512(unsigned short* Asm, const unsigned short* __restrict__ src,
                                           const float* __restrict__ g, const float* __restrict__ bb,
                                           const float* stat, int tid) {
    int row = tid & 31, kb = (tid >> 5) * 64;
    float mean = stat[row], rstd = stat[32 + row];
#pragma unroll 2
    for (int c = 0; c < 8; ++c) {
        int k = kb + c * 8;
        ushort4 u0 = ldc_us4(src + (size_t)row * 1024 + k);
        ushort4 u1 = ldc_us4(src + (size_t)row * 1024 + k + 4);
        float4 g0 = *reinterpret_cast<const float4*>(g + k);
        float4 g1 = *reinterpret_cast<const float4*>(g + k + 4);
        float4 b0 = *reinterpret_cast<const float4*>(bb + k);
        float4 b1 = *reinterpret_cast<const float4*>(bb + k + 4);
        ushort4 o0, o1;
        o0.x = f2bf(eluf((bf2f(u0.x) - mean) * rstd * g0.x + b0.x));
        o0.y = f2bf(eluf((bf2f(u0.y) - mean) * rstd * g0.y + b0.y));
        o0.z = f2bf(eluf((bf2f(u0.z) - mean) * rstd * g0.z + b0.z));
        o0.w = f2bf(eluf((bf2f(u0.w) - mean) * rstd * g0.w + b0.w));
        o1.x = f2bf(eluf((bf2f(u1.x) - mean) * rstd * g1.x + b1.x));
        o1.y = f2bf(eluf((bf2f(u1.y) - mean) * rstd * g1.y + b1.y));
        o1.z = f2bf(eluf((bf2f(u1.z) - mean) * rstd * g1.z + b1.z));
        o1.w = f2bf(eluf((bf2f(u1.w) - mean) * rstd * g1.w + b1.w));
        *reinterpret_cast<ushort4*>(Asm + row * 1032 + k) = o0;
        *reinterpret_cast<ushort4*>(Asm + row * 1032 + k + 4) = o1;
    }
}

__global__ __launch_bounds__(512, 1) void k_scan(ScanArgs a) {
    // 93184 B > 80 KiB -> 1 block/CU; grid 256 <= 256 CUs -> all co-resident.
    __shared__ char smem[93184];
    unsigned short* Asm = (unsigned short*)smem;       // 66048 B: 32 x 1032 bf16
    float* cbuf  = (float*)(smem + 66048);             // 24576 B region
    float* stat  = (float*)(smem + 66048 + 8192);      // P4 stats (512 B, after cb4's 8 KB)
    float* stat2 = (float*)(smem + 90624);             // P2 stats (512 B)
    float* hbuf  = (float*)(smem + 91136);             // P2 combine out (2048 B)

    const int bid = blockIdx.x;
    const int tid = threadIdx.x;
    const int w = tid >> 6, l = tid & 63, l15 = l & 15, kg = l >> 4;
    int epoch = 0;

    for (int t = 0; t < NSTEP; ++t) {
        const float* preA_t = a.postsPreA + (size_t)t * 32768;
        const float* preE_t = a.priorsPreE + (size_t)t * 32768;
        float* posts_t = a.postsPreA + (size_t)t * 32768;
        float* samples_t = a.samples + (size_t)t * 16384;
        float* feats_t = a.feats + (size_t)t * 81920;
        const float* featsPrev = a.feats + (size_t)(t - 1) * 81920;
        const unsigned short* h16cur = (t & 1) ? a.h16m1 : a.h16m0;
        unsigned short* h16nxt = (t & 1) ? a.h16m0 : a.h16m1;

        // ---------- P1 (r14 verbatim): x1 = preA + (m z)@Wz^T, 64 blocks
        if (bid < 64) {
            int j0 = bid * 16;
            if (tid < 256) {
                const unsigned short* A0 = a.z16m + l15 * 512 + w * 128 + kg * 8;
                const unsigned short* A1 = A0 + 16 * 512;
                const unsigned short* Bp = a.Wz16 + (size_t)(j0 + l15) * 512 + w * 128 + kg * 8;
                f32x4 c0 = {0,0,0,0}, c1 = {0,0,0,0};
#pragma unroll
                for (int ks = 0; ks < 4; ++ks) {
                    bf16x8 b = *reinterpret_cast<const bf16x8*>(Bp + ks * 32);
                    c0 = MFMA16(ldc_bf8(A0 + ks * 32), b, c0, 0, 0, 0);
                    c1 = MFMA16(ldc_bf8(A1 + ks * 32), b, c1, 0, 0, 0);
                }
#pragma unroll
                for (int i = 0; i < 4; ++i) {
                    cbuf[w * 512 + (kg * 4 + i) * 16 + l15] = c0[i];
                    cbuf[w * 512 + (16 + kg * 4 + i) * 16 + l15] = c1[i];
                }
            }
            __syncthreads();
            if (tid < 256) {
                int r = tid >> 3, c2 = (tid & 7) * 2;
                int base = r * 16 + c2;
                float v0 = cbuf[base] + cbuf[512 + base] + cbuf[1024 + base] + cbuf[1536 + base]
                         + preA_t[r * 1024 + j0 + c2];
                float v1 = cbuf[base + 1] + cbuf[512 + base + 1] + cbuf[1024 + base + 1] + cbuf[1536 + base + 1]
                         + preA_t[r * 1024 + j0 + c2 + 1];
                unsigned short u0 = f2bf(v0), u1 = f2bf(v1);
                stc_u32((unsigned*)(a.x1b + (size_t)r * 1024 + j0 + c2),
                        (unsigned)u0 | ((unsigned)u1 << 16));
                float w0 = bf2f(u0), w1 = bf2f(u1);
                float s = w0 + w1, q = w0 * w0 + w1 * w1;
                s += __shfl_xor(s, 1); q += __shfl_xor(q, 1);
                s += __shfl_xor(s, 2); q += __shfl_xor(q, 2);
                s += __shfl_xor(s, 4); q += __shfl_xor(q, 4);
                if ((tid & 7) == 0) {
                    union { float f[2]; unsigned long long u; } pu;
                    pu.f[0] = s; pu.f[1] = q;
                    stc_u64((unsigned long long*)(a.x1parts + ((size_t)bid * 32 + r) * 2), pu.u);
                }
            }
        }
        epoch++; gbar3(a.flags, a.release, epoch);

        // ---------- P2 (r14 K-split + parallel stats/fill): gates + combine, 128 blocks
        if (bid < 128) {
            int j0 = bid * 16;
            ln_stats2(a.x1parts, stat2, cbuf, tid);
            __syncthreads();
            ln_fill512(Asm, a.x1b, a.ln_in_g, a.ln_in_b, stat2, tid);
            __syncthreads();
            f32x4 cr = {0,0,0,0}, cu = {0,0,0,0}, cn = {0,0,0,0};
            if (w < 4) {
                int rowgrp = w & 1, kh = w >> 1;
                const unsigned short* ap = Asm + (rowgrp * 16 + l15) * 1032 + kh * 512 + kg * 8;
                const unsigned short* br = a.Wih16 + (size_t)(j0 + l15) * 1024 + kh * 512 + kg * 8;
                const unsigned short* bu = br + (size_t)2048 * 1024;
                const unsigned short* bn = bu + (size_t)2048 * 1024;
#pragma unroll 4
                for (int ks = 0; ks < 16; ++ks) {
                    bf16x8 av = *reinterpret_cast<const bf16x8*>(ap + ks * 32);
                    cr = MFMA16(av, *reinterpret_cast<const bf16x8*>(br + ks * 32), cr, 0, 0, 0);
                    cu = MFMA16(av, *reinterpret_cast<const bf16x8*>(bu + ks * 32), cu, 0, 0, 0);
                    cn = MFMA16(av, *reinterpret_cast<const bf16x8*>(bn + ks * 32), cn, 0, 0, 0);
                }
            } else {
                int idx = w - 4, rowgrp = idx & 1, kh = idx >> 1;
                const unsigned short* hp = h16cur + (size_t)(rowgrp * 16 + l15) * 2048 + kh * 1024 + kg * 8;
                const unsigned short* br = a.Whh16 + (size_t)(j0 + l15) * 2048 + kh * 1024 + kg * 8;
                const unsigned short* bu = br + (size_t)2048 * 2048;
                const unsigned short* bn = bu + (size_t)2048 * 2048;
#pragma unroll 4
                for (int ks = 0; ks < 32; ++ks) {
                    bf16x8 av = ldc_bf8(hp + ks * 32);
                    cr = MFMA16(av, *reinterpret_cast<const bf16x8*>(br + ks * 32), cr, 0, 0, 0);
                    cu = MFMA16(av, *reinterpret_cast<const bf16x8*>(bu + ks * 32), cu, 0, 0, 0);
                    cn = MFMA16(av, *reinterpret_cast<const bf16x8*>(bn + ks * 32), cn, 0, 0, 0);
                }
            }
#pragma unroll
            for (int i = 0; i < 4; ++i) {
                int o = (kg * 4 + i) * 16 + l15;
                cbuf[w * 768 + 0 * 256 + o] = cr[i];
                cbuf[w * 768 + 1 * 256 + o] = cu[i];
                cbuf[w * 768 + 2 * 256 + o] = cn[i];
            }
            __syncthreads();
            {
                int row = tid >> 4, col = tid & 15;
                int rowgrp = row >> 4, rr = row & 15;
                int o = rr * 16 + col;
                int j = j0 + col;
                float gr = cbuf[rowgrp * 768 + 0 * 256 + o] + cbuf[(2 + rowgrp) * 768 + 0 * 256 + o] + a.bih[j];
                float gu = cbuf[rowgrp * 768 + 1 * 256 + o] + cbuf[(2 + rowgrp) * 768 + 1 * 256 + o] + a.bih[j + 2048];
                float gn = cbuf[rowgrp * 768 + 2 * 256 + o] + cbuf[(2 + rowgrp) * 768 + 2 * 256 + o] + a.bih[j + 4096];
                float hr = cbuf[(4 + rowgrp) * 768 + 0 * 256 + o] + cbuf[(6 + rowgrp) * 768 + 0 * 256 + o] + a.bhh[j];
                float hu = cbuf[(4 + rowgrp) * 768 + 1 * 256 + o] + cbuf[(6 + rowgrp) * 768 + 1 * 256 + o] + a.bhh[j + 2048];
                float hn = cbuf[(4 + rowgrp) * 768 + 2 * 256 + o] + cbuf[(6 + rowgrp) * 768 + 2 * 256 + o] + a.bhh[j + 4096];
                float r_ = sigf(gr + hr), u_ = sigf(gu + hu);
                float cand = tanhf(gn + r_ * hn);
                float m = a.reset[t * 32 + row] ? 0.f : 1.f;
                float hpv = (t == 0) ? a.h0m[(size_t)row * 2048 + j]
                                     : ldc_f32(featsPrev + (size_t)row * 2560 + j);
                hbuf[row * 16 + col] = (1.f - u_) * cand + u_ * (m * hpv);
            }
            __syncthreads();
            if (tid < 256) {
                int b = tid >> 3, c2 = (tid & 7) * 2;
                float h0v = hbuf[b * 16 + c2], h1v = hbuf[b * 16 + c2 + 1];
                int j = j0 + c2;
                union { float f[2]; unsigned long long u; } fu;
                fu.f[0] = h0v; fu.f[1] = h1v;
                stc_u64((unsigned long long*)(feats_t + (size_t)b * 2560 + j), fu.u);
                unsigned short g0 = f2bf(h0v), g1 = f2bf(h1v);
                stc_u32((unsigned*)(a.h16u + (size_t)b * 2048 + j),
                        (unsigned)g0 | ((unsigned)g1 << 16));
                float mn = (t < 63) ? (a.reset[(t + 1) * 32 + b] ? 0.f : 1.f) : 1.f;
                unsigned short n0 = f2bf(h0v * mn), n1 = f2bf(h1v * mn);
                stc_u32((unsigned*)(h16nxt + (size_t)b * 2048 + j),
                        (unsigned)n0 | ((unsigned)n1 << 16));
            }
        }
        epoch++; gbar3(a.flags, a.release, epoch);

        // ---------- P3 (8-wave K-split, r13-verified mapping): x2 = preE + h@Wph^T, 64 blocks
        if (bid < 64) {
            int j0 = bid * 16;
            {
                int rowgrp = w & 1, kq = w >> 1;   // 4 K-quarters of 512
                const unsigned short* Ap = a.h16u + (size_t)(rowgrp * 16 + l15) * 2048 + kq * 512 + kg * 8;
                const unsigned short* Bp = a.Wph16 + (size_t)(j0 + l15) * 2048 + kq * 512 + kg * 8;
                f32x4 c0 = {0,0,0,0};
#pragma unroll 4
                for (int ks = 0; ks < 16; ++ks) {
                    c0 = MFMA16(ldc_bf8(Ap + ks * 32),
                                *reinterpret_cast<const bf16x8*>(Bp + ks * 32), c0, 0, 0, 0);
                }
#pragma unroll
                for (int i = 0; i < 4; ++i)
                    cbuf[w * 256 + (kg * 4 + i) * 16 + l15] = c0[i];
            }
            __syncthreads();
            if (tid < 256) {
                int r = tid >> 3, c2 = (tid & 7) * 2;
                int rowgrp2 = r >> 4, rr = r & 15;
                float v0 = 0.f, v1 = 0.f;
#pragma unroll
                for (int kq2 = 0; kq2 < 4; ++kq2) {
                    v0 += cbuf[(kq2 * 2 + rowgrp2) * 256 + rr * 16 + c2];
                    v1 += cbuf[(kq2 * 2 + rowgrp2) * 256 + rr * 16 + c2 + 1];
                }
                v0 += preE_t[(size_t)r * 1024 + j0 + c2];
                v1 += preE_t[(size_t)r * 1024 + j0 + c2 + 1];
                unsigned short u0 = f2bf(v0), u1 = f2bf(v1);
                stc_u32((unsigned*)(a.x2b + (size_t)r * 1024 + j0 + c2),
                        (unsigned)u0 | ((unsigned)u1 << 16));
                float w0 = bf2f(u0), w1 = bf2f(u1);
                float s = w0 + w1, q = w0 * w0 + w1 * w1;
                s += __shfl_xor(s, 1); q += __shfl_xor(q, 1);
                s += __shfl_xor(s, 2); q += __shfl_xor(q, 2);
                s += __shfl_xor(s, 4); q += __shfl_xor(q, 4);
                if ((tid & 7) == 0) {
                    union { float f[2]; unsigned long long u; } pu;
                    pu.f[0] = s; pu.f[1] = q;
                    stc_u64((unsigned long long*)(a.x2parts + ((size_t)bid * 32 + r) * 2), pu.u);
                }
            }
        }
        epoch++; gbar3(a.flags, a.release, epoch);

        // ---------- P4 (8-wave K-split, r13-verified mapping): post + sample, 32 blocks
        if (bid < 32) {
            int j0 = bid * 16;
            ln_stats2(a.x2parts, stat, cbuf, tid);
            __syncthreads();
            ln_fill512(Asm, a.x2b, a.ln_post_g, a.ln_post_b, stat, tid);
            __syncthreads();
            {
                int tile = w >> 2, mt = (w >> 1) & 1, kh = w & 1;
                const unsigned short* ap = Asm + (mt * 16 + l15) * 1032 + kh * 512 + kg * 8;
                int n = tile ? (512 + j0 + l15) : (j0 + l15);
                const unsigned short* Bp = a.Wpo16 + (size_t)n * 1024 + kh * 512 + kg * 8;
                f32x4 c = {0,0,0,0};
#pragma unroll 4
                for (int ks = 0; ks < 16; ++ks) {
                    c = MFMA16(*reinterpret_cast<const bf16x8*>(ap + ks * 32),
                               *reinterpret_cast<const bf16x8*>(Bp + ks * 32), c, 0, 0, 0);
                }
#pragma unroll
                for (int i = 0; i < 4; ++i)
                    cbuf[w * 256 + (kg * 4 + i) * 16 + l15] = c[i];
            }
            __syncthreads();
            if (tid < 256) {
                int b = tid >> 3, c2 = (tid & 7) * 2;
                int j = j0 + c2;
                int mt2 = b >> 4, rr = b & 15, o = rr * 16;
                float pm0 = cbuf[(mt2 * 2 + 0) * 256 + o + c2] + cbuf[(mt2 * 2 + 1) * 256 + o + c2] + a.b_post[j];
                float pm1 = cbuf[(mt2 * 2 + 0) * 256 + o + c2 + 1] + cbuf[(mt2 * 2 + 1) * 256 + o + c2 + 1] + a.b_post[j + 1];
                float ps0 = cbuf[(4 + mt2 * 2 + 0) * 256 + o + c2] + cbuf[(4 + mt2 * 2 + 1) * 256 + o + c2] + a.b_post[512 + j];
                float ps1 = cbuf[(4 + mt2 * 2 + 0) * 256 + o + c2 + 1] + cbuf[(4 + mt2 * 2 + 1) * 256 + o + c2 + 1] + a.b_post[512 + j + 1];
                posts_t[(size_t)b * 1024 + j] = pm0;
                posts_t[(size_t)b * 1024 + j + 1] = pm1;
                posts_t[(size_t)b * 1024 + 512 + j] = ps0;
                posts_t[(size_t)b * 1024 + 512 + j + 1] = ps1;
                float sp0 = fmaxf(ps0, 0.f) + log1pf(expf(-fabsf(ps0)));
                float sp1 = fmaxf(ps1, 0.f) + log1pf(expf(-fabsf(ps1)));
                float n0v = a.noises[(size_t)t * 16384 + b * 512 + j];
                float n1v = a.noises[(size_t)t * 16384 + b * 512 + j + 1];
                float smp0 = pm0 + (sp0 + 0.1f) * n0v;
                float smp1 = pm1 + (sp1 + 0.1f) * n1v;
                samples_t[(size_t)b * 512 + j] = smp0;
                samples_t[(size_t)b * 512 + j + 1] = smp1;
                feats_t[(size_t)b * 2560 + 2048 + j] = smp0;
                feats_t[(size_t)b * 2560 + 2048 + j + 1] = smp1;
                float mn = (t < 63) ? (a.reset[(t + 1) * 32 + b] ? 0.f : 1.f) : 1.f;
                unsigned short z0_ = f2bf(smp0 * mn), z1_ = f2bf(smp1 * mn);
                stc_u32((unsigned*)(a.z16m + (size_t)b * 512 + j),
                        (unsigned)z0_ | ((unsigned)z1_ << 16));
            }
        }
        epoch++; gbar3(a.flags, a.release, epoch);
    }
}

// ws byte offsets (r12 layout)
#define WS_WZ16   ((size_t)0)
#define WS_WIH16  ((size_t)1048576)
#define WS_WHH16  ((size_t)13631488)
#define WS_WPH16  ((size_t)38797312)
#define WS_WPO16  ((size_t)42991616)
#define WS_Z16M   ((size_t)45088768)
#define WS_H16M0  ((size_t)45121536)
#define WS_H16M1  ((size_t)45252608)
#define WS_H16U   ((size_t)45383680)
#define WS_H0M    ((size_t)45514752)
#define WS_X1B    ((size_t)45776896)
#define WS_X2B    ((size_t)45842432)
#define WS_X1P    ((size_t)45907968)
#define WS_X2P    ((size_t)45924352)
#define WS_FLAGS  ((size_t)45940736)
#define WS_REL    ((size_t)45973504)
#define WS_PRX    WS_WIH16

extern "C" void kernel_launch(void* const* d_in, const int* in_sizes, int n_in,
                              void* d_out, int out_size, void* d_ws, size_t ws_size,
                              hipStream_t stream)
{
    (void)in_sizes; (void)n_in; (void)out_size; (void)ws_size;
    const float*   embed  = (const float*)d_in[0];
    const float*   action = (const float*)d_in[1];
    const uint8_t* reset  = (const uint8_t*)d_in[2];
    const float*   h0     = (const float*)d_in[3];
    const float*   z0     = (const float*)d_in[4];
    const float*   noises = (const float*)d_in[5];
    const float*   W_z    = (const float*)d_in[6];
    const float*   b_z    = (const float*)d_in[7];
    const float*   W_a    = (const float*)d_in[8];
    const float*   ln_in_g = (const float*)d_in[9];
    const float*   ln_in_b = (const float*)d_in[10];
    const float*   Wih    = (const float*)d_in[11];
    const float*   Whh    = (const float*)d_in[12];
    const float*   bih    = (const float*)d_in[13];
    const float*   bhh    = (const float*)d_in[14];
    const float*   W_ph   = (const float*)d_in[15];
    const float*   b_ph   = (const float*)d_in[16];
    const float*   W_pe   = (const float*)d_in[17];
    const float*   ln_post_g = (const float*)d_in[18];
    const float*   ln_post_b = (const float*)d_in[19];
    const float*   W_post = (const float*)d_in[20];
    const float*   b_post = (const float*)d_in[21];
    const float*   W_prh  = (const float*)d_in[22];
    const float*   b_prh  = (const float*)d_in[23];
    const float*   ln_pr_g = (const float*)d_in[24];
    const float*   ln_pr_b = (const float*)d_in[25];
    const float*   W_pr   = (const float*)d_in[26];
    const float*   b_pr   = (const float*)d_in[27];

    float* out     = (float*)d_out;
    float* priors  = out;                  // preE lives here during scan
    float* posts   = out + 2097152;        // preA lives here during scan
    float* samples = out + 4194304;
    float* feats   = out + 5242880;
    float* hlast   = out + 10485760;
    float* zlast   = out + 10551296;

    char* ws = (char*)d_ws;
    unsigned short* Wz16  = (unsigned short*)(ws + WS_WZ16);
    unsigned short* Wih16 = (unsigned short*)(ws + WS_WIH16);
    unsigned short* Whh16 = (unsigned short*)(ws + WS_WHH16);
    unsigned short* Wph16 = (unsigned short*)(ws + WS_WPH16);
    unsigned short* Wpo16 = (unsigned short*)(ws + WS_WPO16);
    unsigned short* z16m  = (unsigned short*)(ws + WS_Z16M);
    unsigned short* h16m0 = (unsigned short*)(ws + WS_H16M0);
    unsigned short* h16m1 = (unsigned short*)(ws + WS_H16M1);
    unsigned short* h16u  = (unsigned short*)(ws + WS_H16U);
    float*          h0m   = (float*)(ws + WS_H0M);
    unsigned short* x1b   = (unsigned short*)(ws + WS_X1B);
    unsigned short* x2b   = (unsigned short*)(ws + WS_X2B);
    float*          x1p   = (float*)(ws + WS_X1P);
    float*          x2p   = (float*)(ws + WS_X2P);
    int*            flags = (int*)(ws + WS_FLAGS);
    int*            release = (int*)(ws + WS_REL);
    float*          prx   = (float*)(ws + WS_PRX);

    dim3 blk(256);

    k_cvt_all<<<dim3(22016), blk, 0, stream>>>(W_z, Wz16, Wih, Wih16, Whh, Whh16,
                                               W_ph, Wph16, W_post, Wpo16);
    k_setup<<<dim3(80), blk, 0, stream>>>(h0, z0, reset, h0m, h16m0, z16m, flags);

    // preA -> posts region ; preE -> priors region
    k_preA<<<dim3(2048), blk, 0, stream>>>(action, W_a, b_z, posts);
    gemm_mfma<<<dim3(16, 32), blk, 0, stream>>>(embed, EMBED_D, W_pe, EMBED_D, b_ph,
                                                priors, HIDDEN, EMBED_D);

    ScanArgs sa;
    sa.Wz16 = Wz16; sa.Wih16 = Wih16; sa.Whh16 = Whh16; sa.Wph16 = Wph16; sa.Wpo16 = Wpo16;
    sa.bih = bih; sa.bhh = bhh; sa.b_post = b_post;
    sa.ln_in_g = ln_in_g; sa.ln_in_b = ln_in_b; sa.ln_post_g = ln_post_g; sa.ln_post_b = ln_post_b;
    sa.h0m = h0m; sa.reset = reset; sa.noises = noises;
    sa.postsPreA = posts; sa.priorsPreE = priors; sa.samples = samples; sa.feats = feats;
    sa.z16m = z16m; sa.x1b = x1b; sa.x2b = x2b; sa.h16u = h16u;
    sa.h16m0 = h16m0; sa.h16m1 = h16m1;
    sa.x1parts = x1p; sa.x2parts = x2p;
    sa.flags = flags; sa.release = release;

    // Plain launch: 256 blocks x 512 threads; LDS 93184 B -> 1 block/CU, all co-resident.
    k_scan<<<dim3(NBLK), dim3(512), 0, stream>>>(sa);

    // prior chain
    gemm_mfma<<<dim3(16, 32), blk, 0, stream>>>(feats, FEAT, W_prh, DETER, b_prh,
                                                prx, HIDDEN, DETER);
    ln_elu_rows<<<dim3(2048), blk, 0, stream>>>(prx, ln_pr_g, ln_pr_b);
    gemm_mfma<<<dim3(16, 32), blk, 0, stream>>>(prx, HIDDEN, W_pr, HIDDEN, b_pr,
                                                priors, HIDDEN, HIDDEN);

    k_copy_last<<<dim3(256), blk, 0, stream>>>(
        feats + (size_t)(NSTEP - 1) * BATCH * FEAT,
        samples + (size_t)(NSTEP - 1) * BATCH * STOCH,
        hlast, zlast);
}